// Round 8
// baseline (678.646 us; speedup 1.0000x reference)
//
#include <hip/hip_runtime.h>
#include <hip/hip_bf16.h>
#include <math.h>

using bf16 = __hip_bfloat16;
#define DEV static __device__ __forceinline__

typedef float    fx4   __attribute__((ext_vector_type(4)));
typedef float    fx2   __attribute__((ext_vector_type(2)));
typedef short    s16x8 __attribute__((ext_vector_type(8)));
typedef short    s16x4 __attribute__((ext_vector_type(4)));
typedef __bf16   bfx8  __attribute__((ext_vector_type(8)));
typedef unsigned int u32x4 __attribute__((ext_vector_type(4)));

constexpr int BATCH = 8;
constexpr int NPIX  = 16384;      // 128x128
constexpr int KFF   = 352;        // padded K for ffn_out
constexpr int MFI   = 768;        // padded M for ffn_in (true 680)
constexpr int H1S   = 704;        // h1 stride: halves at 0 and 352

DEV float uu2f(unsigned short u) { return __uint_as_float(((unsigned)u) << 16); }
DEV unsigned short f2us(float f) { bf16 h = __float2bfloat16(f); return *(unsigned short*)&h; }
DEV float bl2f(bf16 v) { return __bfloat162float(v); }

// ---------------- workspace layout (bytes) ----------------
constexpr size_t OFF_SL1   = 0;                    // {xnext,up,xprev} -> qkv_a -> h1
constexpr size_t OFF_XNEXT = OFF_SL1;              // 16.78MB
constexpr size_t OFF_UP    = OFF_SL1 + 16777216;   // 33.55MB
constexpr size_t OFF_XPREV = OFF_SL1 + 50331648;   // 67.1MB
constexpr size_t SZ_SL1    = 184549376;            // h1 = 8*16384*704*2
constexpr size_t OFF_SL2   = OFF_SL1 + SZ_SL1;     // qkv_b -> g
constexpr size_t OFF_SL3   = OFF_SL2 + 100663296;  // y1
constexpr size_t OFF_SL4   = OFF_SL3 + 33554432;   // x (bf16 pm)
constexpr size_t OFF_SL5   = OFF_SL4 + 33554432;   // y2
constexpr size_t OFF_W     = OFF_SL5 + 33554432;
constexpr size_t OFF_WUP   = OFF_W;                // 512*256*2
constexpr size_t OFF_WQKV  = OFF_W +  262144;      // 384*128*2
constexpr size_t OFF_WPRJ  = OFF_W +  360448;      // 128*128*2
constexpr size_t OFF_WFIN  = OFF_W +  393216;      // 768*128*2
constexpr size_t OFF_WFOUT = OFF_W +  589824;      // 128*352*2
constexpr size_t OFF_WTAP  = OFF_W +  679936;      // 9*128*64*2
constexpr size_t OFF_ZP    = OFF_W +  827392;      // 256B zero page
constexpr size_t OFF_NBUF  = OFF_W +  974848;      // 8*256*4
constexpr size_t OFF_S     = OFF_W +  983040;      // 32*1024*4 (contiguous after nbuf)
constexpr size_t OFF_W2    = OFF_W + 1114112;      // 8*128*128*2

// ---------------------------------------------------------------------------
// one-shot prep: weight converts/permutes + zero fills (replaces 6 kernels + 2 memsets)
// segments: Wup | Wqkv | Wprj | Wfin | Wfout | Wtap | zero(nbuf+S) | zpage
// ---------------------------------------------------------------------------
__global__ void prep_all(const float* __restrict__ up_w, const float* __restrict__ qkv_w,
                         const float* __restrict__ proj_w, const float* __restrict__ ffn_in_w,
                         const float* __restrict__ ffn_out_w, const float* __restrict__ down_w,
                         bf16* __restrict__ Wup, bf16* __restrict__ Wqkv, bf16* __restrict__ Wprj,
                         bf16* __restrict__ Wfin, bf16* __restrict__ Wfout, bf16* __restrict__ Wtap,
                         float* __restrict__ zf, bf16* __restrict__ zpage)
{
    int i = blockIdx.x * 256 + threadIdx.x;
    if (i < 131072) { Wup[i] = __float2bfloat16(up_w[i]); return; }
    i -= 131072;
    if (i < 49152) { Wqkv[i] = __float2bfloat16(qkv_w[i]); return; }
    i -= 49152;
    if (i < 16384) { Wprj[i] = __float2bfloat16(proj_w[i]); return; }
    i -= 16384;
    if (i < 98304) {              // Wfin 768x128 <- 680x128
        Wfin[i] = (i < 680 * 128) ? __float2bfloat16(ffn_in_w[i]) : bf16(0.f);
        return;
    }
    i -= 98304;
    if (i < 45056) {              // Wfout 128x352 <- 128x340
        int r = i / KFF, c = i % KFF;
        Wfout[i] = (c < 340) ? __float2bfloat16(ffn_out_w[r * 340 + c]) : bf16(0.f);
        return;
    }
    i -= 45056;
    if (i < 73728) {              // Wtap [9][128][64] <- [128][64][9]
        int tap = i >> 13, rm = i & 8191, co = rm >> 6, ci = rm & 63;
        Wtap[i] = __float2bfloat16(down_w[(co * 64 + ci) * 9 + tap]);
        return;
    }
    i -= 73728;
    if (i < 34816) { zf[i] = 0.f; return; }   // nbuf (2048) + S (32768)
    i -= 34816;
    if (i < 128) zpage[i] = bf16(0.f);
}
constexpr int PREP_TOT = 131072 + 49152 + 16384 + 98304 + 45056 + 73728 + 34816 + 128;

// NCHW f32 -> pixel-major bf16 transpose (generic, used for x_next C=256)
__global__ __launch_bounds__(256) void transpose_c2p(
    const float* __restrict__ in, bf16* __restrict__ out, int C, int HW)
{
    __shared__ float ts[32][33];
    int hw0 = blockIdx.x * 32, c0 = blockIdx.y * 32, b = blockIdx.z;
    int rl = threadIdx.x >> 5, cl = threadIdx.x & 31;
#pragma unroll
    for (int i = 0; i < 4; i++)
        ts[rl + i * 8][cl] = in[((size_t)b * C + c0 + rl + i * 8) * HW + hw0 + cl];
    __syncthreads();
#pragma unroll
    for (int i = 0; i < 4; i++)
        out[((size_t)b * HW + hw0 + rl + i * 8) * C + c0 + cl] =
            __float2bfloat16(ts[cl][rl + i * 8]);
}

// x_prev transpose (C=64): full-C output rows -> 128B-line writes
__global__ __launch_bounds__(256) void transpose_prev(
    const float* __restrict__ in, bf16* __restrict__ out)
{
    __shared__ float ts[64][33];
    const int hw0 = blockIdx.x * 32, b = blockIdx.y;
    const int cl = threadIdx.x >> 5, hl = threadIdx.x & 31;
#pragma unroll
    for (int i = 0; i < 8; i++) {
        int c = i * 8 + cl;
        ts[c][hl] = in[((size_t)b * 64 + c) * 65536 + hw0 + hl];
    }
    __syncthreads();
    const int hw = threadIdx.x >> 3, c8 = (threadIdx.x & 7) * 8;
    s16x8 pk;
#pragma unroll
    for (int e = 0; e < 8; e++) pk[e] = (short)f2us(ts[c8 + e][hw]);
    *(s16x8*)((short*)out + ((size_t)b * 65536 + hw0 + hw) * 64 + c8) = pk;
}

// ---------------------------------------------------------------------------
// MFMA GEMM (single m-tile): D[b][n][co] = sum_k Act[b][n][Aoff+k] * Wt[b][co][k]
// EPI 0: store bf16 pm; EPI 1: residual+LN2; EPI 2: residual -> f32 NCHW
// ---------------------------------------------------------------------------
template <int EPI>
__global__ __launch_bounds__(256) void gemm_mfma(
    const bf16* __restrict__ Act, const bf16* __restrict__ Wt,
    int K, int Npb, int Mtrue, int Mstride, int Astride, int Aoff, int WtBS,
    bf16* __restrict__ outB,
    const float* __restrict__ xmain, bf16* __restrict__ x_out,
    const float* __restrict__ nw, const float* __restrict__ nb,
    const bf16* __restrict__ xres, float* __restrict__ outF)
{
    __shared__ short As[128 * 32];
    __shared__ short Bs[128 * 32];
    const int t = threadIdx.x;
    const int w = t >> 6, lane = t & 63;
    const int wr = w >> 1, wc = w & 1;
    const int lr = lane & 15, lg = lane >> 4;
    const int n0 = blockIdx.x * 128;
    const int m0 = blockIdx.y * 128;
    const int b  = blockIdx.z;
    const bf16* Abase = Act + (size_t)b * Npb * Astride + Aoff;
    const bf16* Wtb   = Wt + (size_t)b * WtBS;

    fx4 acc[4][4];
#pragma unroll
    for (int i = 0; i < 4; i++)
#pragma unroll
        for (int j = 0; j < 4; j++) acc[i][j] = fx4{0.f, 0.f, 0.f, 0.f};

    const int f0 = w * 128 + lane, f1 = f0 + 64;
    const int r0 = f0 >> 2, c0 = (f0 & 3) * 8;
    const int r1 = f1 >> 2, c1 = (f1 & 3) * 8;

    for (int ks = 0; ks < K; ks += 32) {
        __builtin_amdgcn_global_load_lds(
            (const __attribute__((address_space(1))) void*)(Abase + (size_t)(n0 + r0) * Astride + ks + c0),
            (__attribute__((address_space(3))) void*)(As + w * 1024), 16, 0, 0);
        __builtin_amdgcn_global_load_lds(
            (const __attribute__((address_space(1))) void*)(Abase + (size_t)(n0 + r1) * Astride + ks + c1),
            (__attribute__((address_space(3))) void*)(As + w * 1024 + 512), 16, 0, 0);
        __builtin_amdgcn_global_load_lds(
            (const __attribute__((address_space(1))) void*)(Wtb + (size_t)(m0 + r0) * K + ks + c0),
            (__attribute__((address_space(3))) void*)(Bs + w * 1024), 16, 0, 0);
        __builtin_amdgcn_global_load_lds(
            (const __attribute__((address_space(1))) void*)(Wtb + (size_t)(m0 + r1) * K + ks + c1),
            (__attribute__((address_space(3))) void*)(Bs + w * 1024 + 512), 16, 0, 0);
        __syncthreads();
        bfx8 af[4], bw[4];
#pragma unroll
        for (int mi = 0; mi < 4; mi++)
            af[mi] = __builtin_bit_cast(bfx8,
                *(const s16x8*)&As[(wr * 64 + mi * 16 + lr) * 32 + lg * 8]);
#pragma unroll
        for (int ni = 0; ni < 4; ni++)
            bw[ni] = __builtin_bit_cast(bfx8,
                *(const s16x8*)&Bs[(wc * 64 + ni * 16 + lr) * 32 + lg * 8]);
#pragma unroll
        for (int mi = 0; mi < 4; mi++)
#pragma unroll
            for (int ni = 0; ni < 4; ni++)
                acc[mi][ni] = __builtin_amdgcn_mfma_f32_16x16x32_bf16(
                    af[mi], bw[ni], acc[mi][ni], 0, 0, 0);
        __syncthreads();
    }

    if (EPI == 0) {
#pragma unroll
        for (int mi = 0; mi < 4; mi++)
#pragma unroll
            for (int ni = 0; ni < 4; ni++) {
                int co = m0 + wc * 64 + ni * 16 + lr;
                if (co < Mtrue) {
#pragma unroll
                    for (int r = 0; r < 4; r++) {
                        int px = n0 + wr * 64 + mi * 16 + lg * 4 + r;
                        outB[((size_t)b * Npb + px) * Mstride + co] =
                            __float2bfloat16(acc[mi][ni][r]);
                    }
                }
            }
    } else if (EPI == 1) {
        float xv[4][4][4];
#pragma unroll
        for (int mi = 0; mi < 4; mi++)
#pragma unroll
            for (int ni = 0; ni < 4; ni++) {
                int co = wc * 64 + ni * 16 + lr;
                fx4 x4 = *(const fx4*)&xmain[((size_t)b * 128 + co) * 16384 +
                                             n0 + wr * 64 + mi * 16 + lg * 4];
#pragma unroll
                for (int r = 0; r < 4; r++) xv[mi][ni][r] = x4[r] + acc[mi][ni][r];
            }
        __shared__ float ps[2][128];
        __shared__ float pss[2][128];
#pragma unroll
        for (int mi = 0; mi < 4; mi++)
#pragma unroll
            for (int r = 0; r < 4; r++) {
                float s = 0.f, s2 = 0.f;
#pragma unroll
                for (int ni = 0; ni < 4; ni++) {
                    float v = xv[mi][ni][r]; s += v; s2 += v * v;
                }
#pragma unroll
                for (int m = 1; m < 16; m <<= 1) {
                    s  += __shfl_xor(s, m);
                    s2 += __shfl_xor(s2, m);
                }
                if (lr == 0) {
                    int row = wr * 64 + mi * 16 + lg * 4 + r;
                    ps[wc][row] = s; pss[wc][row] = s2;
                }
            }
        __syncthreads();
        float nwv[4], nbv[4];
#pragma unroll
        for (int ni = 0; ni < 4; ni++) {
            int co = wc * 64 + ni * 16 + lr;
            nwv[ni] = nw[co]; nbv[ni] = nb[co];
        }
#pragma unroll
        for (int mi = 0; mi < 4; mi++)
#pragma unroll
            for (int r = 0; r < 4; r++) {
                int row = wr * 64 + mi * 16 + lg * 4 + r;
                float s  = ps[0][row] + ps[1][row];
                float s2 = pss[0][row] + pss[1][row];
                float mu = s * (1.f / 128.f);
                float var = s2 * (1.f / 128.f) - mu * mu;
                float rstd = rsqrtf(var + 1e-5f);
                size_t px = (size_t)b * 16384 + n0 + row;
#pragma unroll
                for (int ni = 0; ni < 4; ni++) {
                    int co = wc * 64 + ni * 16 + lr;
                    float v = xv[mi][ni][r];
                    x_out[px * 128 + co] = __float2bfloat16(v);
                    outB[px * 128 + co] = __float2bfloat16((v - mu) * rstd * nwv[ni] + nbv[ni]);
                }
            }
    } else {  // EPI 2
#pragma unroll
        for (int mi = 0; mi < 4; mi++)
#pragma unroll
            for (int ni = 0; ni < 4; ni++) {
                int co = wc * 64 + ni * 16 + lr;
                int pxb = n0 + wr * 64 + mi * 16 + lg * 4;
                fx4 o;
#pragma unroll
                for (int r = 0; r < 4; r++)
                    o[r] = acc[mi][ni][r] +
                           bl2f(xres[((size_t)b * 16384 + pxb + r) * 128 + co]);
                *(fx4*)&outF[((size_t)b * 128 + co) * 16384 + pxb] = o;
            }
    }
}

// ---------------------------------------------------------------------------
// MFMA GEMM with m-tile loop (K=128 fixed): stages full A once, loops B tiles.
// REMAP=1: h1 column remap (co>=340 -> co+12), stride 704, pad cols zeroed.
// ---------------------------------------------------------------------------
template <int REMAP>
__global__ __launch_bounds__(256) void gemm_mloop(
    const bf16* __restrict__ Act, const bf16* __restrict__ Wt,
    int nM, int Mtrue, int Mstride, bf16* __restrict__ outB)
{
    __shared__ short As[16384];   // [4 kb][128 row][32]
    __shared__ short Bs[16384];
    const int t = threadIdx.x;
    const int w = t >> 6, lane = t & 63;
    const int wr = w >> 1, wc = w & 1;
    const int lr = lane & 15, lg = lane >> 4;
    const int n0 = blockIdx.x * 128;
    const int b  = blockIdx.y;
    const short* Abase = (const short*)Act + (size_t)b * NPIX * 128;

#pragma unroll
    for (int i = 0; i < 8; i++) {
        int chunk = i * 256 + w * 64 + lane;
        int kb = chunk >> 9, row = (chunk >> 2) & 127, c8 = chunk & 3;
        __builtin_amdgcn_global_load_lds(
            (const __attribute__((address_space(1))) void*)
                (Abase + (size_t)(n0 + row) * 128 + kb * 32 + c8 * 8),
            (__attribute__((address_space(3))) void*)(As + i * 2048 + w * 512), 16, 0, 0);
    }

    for (int mt = 0; mt < nM; mt++) {
#pragma unroll
        for (int i = 0; i < 8; i++) {
            int chunk = i * 256 + w * 64 + lane;
            int kb = chunk >> 9, row = (chunk >> 2) & 127, c8 = chunk & 3;
            __builtin_amdgcn_global_load_lds(
                (const __attribute__((address_space(1))) void*)
                    ((const short*)Wt + (size_t)(mt * 128 + row) * 128 + kb * 32 + c8 * 8),
                (__attribute__((address_space(3))) void*)(Bs + i * 2048 + w * 512), 16, 0, 0);
        }
        __syncthreads();
        fx4 acc[4][4];
#pragma unroll
        for (int i = 0; i < 4; i++)
#pragma unroll
            for (int j = 0; j < 4; j++) acc[i][j] = fx4{0.f, 0.f, 0.f, 0.f};
#pragma unroll
        for (int ks = 0; ks < 4; ks++) {
            bfx8 af[4], bw[4];
#pragma unroll
            for (int mi = 0; mi < 4; mi++)
                af[mi] = __builtin_bit_cast(bfx8,
                    *(const s16x8*)&As[ks * 4096 + (wr * 64 + mi * 16 + lr) * 32 + lg * 8]);
#pragma unroll
            for (int ni = 0; ni < 4; ni++)
                bw[ni] = __builtin_bit_cast(bfx8,
                    *(const s16x8*)&Bs[ks * 4096 + (wc * 64 + ni * 16 + lr) * 32 + lg * 8]);
#pragma unroll
            for (int mi = 0; mi < 4; mi++)
#pragma unroll
                for (int ni = 0; ni < 4; ni++)
                    acc[mi][ni] = __builtin_amdgcn_mfma_f32_16x16x32_bf16(
                        af[mi], bw[ni], acc[mi][ni], 0, 0, 0);
        }
        __syncthreads();
#pragma unroll
        for (int mi = 0; mi < 4; mi++)
#pragma unroll
            for (int ni = 0; ni < 4; ni++) {
                int co = mt * 128 + wc * 64 + ni * 16 + lr;
                if (co < Mtrue) {
                    int cd = (REMAP && co >= 340) ? co + 12 : co;
#pragma unroll
                    for (int r = 0; r < 4; r++) {
                        int px = n0 + wr * 64 + mi * 16 + lg * 4 + r;
                        outB[((size_t)b * NPIX + px) * Mstride + cd] =
                            __float2bfloat16(acc[mi][ni][r]);
                    }
                    if (REMAP && co >= 340 && co < 352) {
#pragma unroll
                        for (int r = 0; r < 4; r++) {
                            int px = n0 + wr * 64 + mi * 16 + lg * 4 + r;
                            outB[((size_t)b * NPIX + px) * Mstride + co] = bf16(0.f);
                        }
                    }
                } else if (REMAP && co < 692) {    // zero pad cols 692..703
#pragma unroll
                    for (int r = 0; r < 4; r++) {
                        int px = n0 + wr * 64 + mi * 16 + lg * 4 + r;
                        outB[((size_t)b * NPIX + px) * Mstride + co + 12] = bf16(0.f);
                    }
                }
            }
    }
}

// ---------------------------------------------------------------------------
// down-conv(3x3,s2) as 9-tap MFMA GEMM + residual + pixel-shuffle + LN1 -> y1
// ---------------------------------------------------------------------------
__global__ __launch_bounds__(256) void down_mfma_ln(
    const bf16* __restrict__ xprev_pm,   // [b][65536][64]
    const float* __restrict__ xmain,     // NCHW f32
    const bf16* __restrict__ up_pm,      // [b][4096][512]
    const bf16* __restrict__ wtap,       // [9][128co][64ci]
    const float* __restrict__ alpha_d, const float* __restrict__ alpha_u,
    const float* __restrict__ n1w, const float* __restrict__ n1b,
    const bf16* __restrict__ zeropage,
    bf16* __restrict__ y1)               // [b][16384][128]
{
    __shared__ short As[128 * 64];
    __shared__ short Bs[128 * 64];
    __shared__ float ps[2][128];
    __shared__ float pss[2][128];
    const int t = threadIdx.x;
    const int w = t >> 6, lane = t & 63;
    const int wr = w >> 1, wc = w & 1;
    const int lr = lane & 15, lg = lane >> 4;
    const int y = blockIdx.x;
    const int b = blockIdx.y;

    const int srow0 = 32 * w + (lane >> 3);
    const int sci8  = lane & 7;
    const short* wtbase = (const short*)wtap;

    fx4 acc[4][4];
#pragma unroll
    for (int i = 0; i < 4; i++)
#pragma unroll
        for (int j = 0; j < 4; j++) acc[i][j] = fx4{0.f, 0.f, 0.f, 0.f};

#pragma unroll
    for (int tap = 0; tap < 9; tap++) {
        const int dy = tap / 3, dx = tap % 3;
        const int iy = 2 * y - 1 + dy;
        const bool rowok = (iy >= 0) && (iy < 256);
        const short* arow = (const short*)xprev_pm +
                            (((size_t)b * 65536 + (size_t)iy * 256) * 64);
#pragma unroll
        for (int i = 0; i < 4; i++) {
            int row = srow0 + 8 * i;
            int ix = 2 * row - 1 + dx;
            const short* src = (rowok && ix >= 0 && ix < 256)
                                 ? (arow + (size_t)ix * 64 + sci8 * 8)
                                 : (const short*)zeropage;
            __builtin_amdgcn_global_load_lds(
                (const __attribute__((address_space(1))) void*)src,
                (__attribute__((address_space(3))) void*)(As + w * 2048 + i * 512), 16, 0, 0);
            __builtin_amdgcn_global_load_lds(
                (const __attribute__((address_space(1))) void*)
                    (wtbase + tap * 8192 + w * 2048 + i * 512 + lane * 8),
                (__attribute__((address_space(3))) void*)(Bs + w * 2048 + i * 512), 16, 0, 0);
        }
        __syncthreads();
        bfx8 af[4][2], bw[4][2];
#pragma unroll
        for (int mi = 0; mi < 4; mi++)
#pragma unroll
            for (int ks = 0; ks < 2; ks++)
                af[mi][ks] = __builtin_bit_cast(bfx8,
                    *(const s16x8*)&As[(wr * 64 + mi * 16 + lr) * 64 + ks * 32 + lg * 8]);
#pragma unroll
        for (int ni = 0; ni < 4; ni++)
#pragma unroll
            for (int ks = 0; ks < 2; ks++)
                bw[ni][ks] = __builtin_bit_cast(bfx8,
                    *(const s16x8*)&Bs[(wc * 64 + ni * 16 + lr) * 64 + ks * 32 + lg * 8]);
#pragma unroll
        for (int mi = 0; mi < 4; mi++)
#pragma unroll
            for (int ni = 0; ni < 4; ni++)
#pragma unroll
                for (int ks = 0; ks < 2; ks++)
                    acc[mi][ni] = __builtin_amdgcn_mfma_f32_16x16x32_bf16(
                        af[mi][ks], bw[ni][ks], acc[mi][ni], 0, 0, 0);
        __syncthreads();
    }

    const float ad = alpha_d[0], au = alpha_u[0];
    const int n2base = (y >> 1) * 64;
    const int chb2 = (y & 1) * 2;
    float fv[4][4][4];
#pragma unroll
    for (int mi = 0; mi < 4; mi++) {
        const int x0 = wr * 64 + mi * 16 + lg * 4;
#pragma unroll
        for (int ni = 0; ni < 4; ni++) {
            const int co = wc * 64 + ni * 16 + lr;
            fx4 xm = *(const fx4*)&xmain[(((size_t)b * 128 + co) * 128 + y) * 128 + x0];
            const short* uprow = (const short*)up_pm +
                ((size_t)b * 4096 + n2base + (x0 >> 1)) * 512 + co * 4 + chb2;
            unsigned up01 = *(const unsigned*)uprow;
            unsigned up23 = *(const unsigned*)(uprow + 512);
            fv[mi][ni][0] = xm[0] + ad * acc[mi][ni][0] + au * uu2f((unsigned short)(up01 & 0xffff));
            fv[mi][ni][1] = xm[1] + ad * acc[mi][ni][1] + au * uu2f((unsigned short)(up01 >> 16));
            fv[mi][ni][2] = xm[2] + ad * acc[mi][ni][2] + au * uu2f((unsigned short)(up23 & 0xffff));
            fv[mi][ni][3] = xm[3] + ad * acc[mi][ni][3] + au * uu2f((unsigned short)(up23 >> 16));
        }
    }
#pragma unroll
    for (int mi = 0; mi < 4; mi++)
#pragma unroll
        for (int r = 0; r < 4; r++) {
            float s = 0.f, s2 = 0.f;
#pragma unroll
            for (int ni = 0; ni < 4; ni++) {
                float v = fv[mi][ni][r]; s += v; s2 += v * v;
            }
#pragma unroll
            for (int m = 1; m < 16; m <<= 1) {
                s  += __shfl_xor(s, m);
                s2 += __shfl_xor(s2, m);
            }
            if (lr == 0) {
                int row = wr * 64 + mi * 16 + lg * 4 + r;
                ps[wc][row] = s; pss[wc][row] = s2;
            }
        }
    __syncthreads();
    float nwv[4], nbv[4];
#pragma unroll
    for (int ni = 0; ni < 4; ni++) {
        int co = wc * 64 + ni * 16 + lr;
        nwv[ni] = n1w[co]; nbv[ni] = n1b[co];
    }
#pragma unroll
    for (int mi = 0; mi < 4; mi++)
#pragma unroll
        for (int r = 0; r < 4; r++) {
            int row = wr * 64 + mi * 16 + lg * 4 + r;
            float s  = ps[0][row] + ps[1][row];
            float s2 = pss[0][row] + pss[1][row];
            float mu = s * (1.f / 128.f);
            float var = s2 * (1.f / 128.f) - mu * mu;
            float rstd = rsqrtf(var + 1e-5f);
            size_t px = (size_t)b * 16384 + (size_t)y * 128 + row;
#pragma unroll
            for (int ni = 0; ni < 4; ni++) {
                int co = wc * 64 + ni * 16 + lr;
                ((short*)y1)[px * 128 + co] =
                    (short)f2us((fv[mi][ni][r] - mu) * rstd * nwv[ni] + nbv[ni]);
            }
        }
}

// ---------------------------------------------------------------------------
// depthwise 3x3 accumulator, templated on YT2 (output rows per thread).
// L: [NROWS][34 pos][44 ch-shorts] (88B = 22 banks -> 2-way free), swb: [9][32] f32
// ---------------------------------------------------------------------------
template <int YT2>
DEV void dw_accum(const short* __restrict__ L, const float* __restrict__ swb,
                  int x, int yh, int lofs, fx2 acc[YT2][4])
{
    fx2 wreg[9][4];
#pragma unroll
    for (int tap = 0; tap < 9; tap++)
#pragma unroll
        for (int k = 0; k < 4; k++)
            wreg[tap][k] = *(const fx2*)&swb[tap * 32 + lofs + 2 * k];
#pragma unroll
    for (int yy = 0; yy < YT2; yy++)
#pragma unroll
        for (int k = 0; k < 4; k++) acc[yy][k] = fx2{0.f, 0.f};
#pragma unroll
    for (int r = 0; r < YT2 + 2; r++) {
        fx2 rv[3][4];
#pragma unroll
        for (int dxp = 0; dxp < 3; dxp++) {
            s16x8 raw = *(const s16x8*)&L[((yh * YT2 + r) * 34 + x + dxp) * 44 + lofs];
            u32x4 u = __builtin_bit_cast(u32x4, raw);
#pragma unroll
            for (int k = 0; k < 4; k++)
                rv[dxp][k] = fx2{__uint_as_float(u[k] << 16),
                                 __uint_as_float(u[k] & 0xffff0000u)};
        }
#pragma unroll
        for (int yy = 0; yy < YT2; yy++) {
            int dy = r - yy;
            if (dy < 0 || dy > 2) continue;
#pragma unroll
            for (int dx = 0; dx < 3; dx++)
#pragma unroll
                for (int k = 0; k < 4; k++)
                    acc[yy][k] += rv[dx][k] * wreg[dy * 3 + dx][k];
        }
    }
}

// ---------------------------------------------------------------------------
// depthwise 3x3 pad=1, pixel-major. GATE=1: gelu(dw(h1a)) * dw(h1b) (both
// halves staged at once, proven pattern); GATE=0: plain (qkv) + q/k sumsq.
// grid: (cg, spatial, b) -- cg innermost so concurrent blocks share lines.
// ---------------------------------------------------------------------------
template <int GATE, int QKNORM, int YTILE>
__global__ __launch_bounds__(256) void dw_conv(
    const bf16* __restrict__ in, const float* __restrict__ w,
    bf16* __restrict__ out, float* __restrict__ nbuf)
{
    constexpr int CHST  = GATE ? 704 : 384;
    constexpr int CHOST = GATE ? 352 : 384;
    constexpr int NROWS = YTILE + 2;
    constexpr int YT2   = YTILE / 2;
    constexpr int LSZ   = NROWS * 34 * 44;
    __shared__ short L1[LSZ];
    __shared__ short L2[GATE ? LSZ : 8];
    __shared__ float sw1[288];                  // [9][32]
    __shared__ float sw2[GATE ? 288 : 8];
    __shared__ float snorm[QKNORM ? 32 : 8];
    const int t = threadIdx.x;
    const int x = t & 31, chg = (t >> 5) & 3, yh = t >> 7;
    const int cg = blockIdx.x, b = blockIdx.z;
    const int sp = blockIdx.y;
    const int x0 = (sp & 3) * 32, y0 = (sp >> 2) * YTILE;

    if (QKNORM && t < 32) snorm[t] = 0.f;
    if (GATE) {
        for (int i = t; i < 288; i += 256) {
            int c = i & 31, tap = i >> 5;
            int cr = cg * 32 + c;
            sw1[i] = (cr < 340) ? w[cr * 9 + tap] : 0.f;
            sw2[i] = (cr < 340) ? w[(cr + 340) * 9 + tap] : 0.f;
        }
    } else {
        for (int i = t; i < 288; i += 256) {
            int c = i & 31, tap = i >> 5;
            sw1[i] = w[(cg * 32 + c) * 9 + tap];
        }
    }
    const short* bin = (const short*)in + (size_t)b * NPIX * CHST + cg * 32;
    constexpr int NCHK1 = NROWS * 136;
    const int NCHK = GATE ? 2 * NCHK1 : NCHK1;
    for (int id = t; id < NCHK; id += 256) {
        int half = 0, idd = id;
        if (GATE && idd >= NCHK1) { half = 1; idd -= NCHK1; }
        int row = idd / 136, rm = idd % 136, pos = rm >> 2, c8 = rm & 3;
        int gy = y0 - 1 + row, gx = x0 - 1 + pos;
        s16x8 v = s16x8{0, 0, 0, 0, 0, 0, 0, 0};
        if (gy >= 0 && gy < 128 && gx >= 0 && gx < 128)
            v = *(const s16x8*)(bin + ((size_t)(gy << 7) + gx) * CHST + half * 352 + c8 * 8);
        short* dst = (GATE && half) ? L2 : L1;
        *(s16x8*)&dst[(row * 34 + pos) * 44 + c8 * 8] = v;
    }
    __syncthreads();

    const int lofs = chg * 8;
    fx2 a1[YT2][4];
    dw_accum<YT2>(L1, sw1, x, yh, lofs, a1);
    if (GATE) {
#pragma unroll
        for (int yy = 0; yy < YT2; yy++)
#pragma unroll
            for (int k = 0; k < 4; k++) {
                fx2 v = a1[yy][k];
#pragma unroll
                for (int e = 0; e < 2; e++) {
                    float xx = v[e];
                    float x2 = xx * xx;
                    float mzz = xx * fmaf(-0.1029432f, x2, -2.3022082f);
                    float un = exp2f(mzz);
                    v[e] = xx * __builtin_amdgcn_rcpf(1.f + un);
                }
                a1[yy][k] = v;
            }
        fx2 a2[YT2][4];
        dw_accum<YT2>(L2, sw2, x, yh, lofs, a2);
#pragma unroll
        for (int yy = 0; yy < YT2; yy++)
#pragma unroll
            for (int k = 0; k < 4; k++) a1[yy][k] *= a2[yy][k];
    }

    if (QKNORM && cg < 8) {
        fx2 sq[4];
#pragma unroll
        for (int k = 0; k < 4; k++) {
            sq[k] = fx2{0.f, 0.f};
#pragma unroll
            for (int yy = 0; yy < YT2; yy++) sq[k] += a1[yy][k] * a1[yy][k];
        }
#pragma unroll
        for (int m = 1; m < 32; m <<= 1)
#pragma unroll
            for (int k = 0; k < 4; k++) {
                sq[k][0] += __shfl_xor(sq[k][0], m);
                sq[k][1] += __shfl_xor(sq[k][1], m);
            }
        if (x == 0) {
#pragma unroll
            for (int k = 0; k < 4; k++) {
                atomicAdd(&snorm[chg * 8 + 2 * k],     sq[k][0]);
                atomicAdd(&snorm[chg * 8 + 2 * k + 1], sq[k][1]);
            }
        }
    }

#pragma unroll
    for (int yy = 0; yy < YT2; yy++) {
        s16x8 pk;
#pragma unroll
        for (int k = 0; k < 4; k++) {
            pk[2 * k]     = (short)f2us(a1[yy][k][0]);
            pk[2 * k + 1] = (short)f2us(a1[yy][k][1]);
        }
        *(s16x8*)((short*)out + (((size_t)b * NPIX) + ((y0 + yh * YT2 + yy) << 7) + x0 + x) * CHOST
                  + cg * 32 + chg * 8) = pk;
    }

    if (QKNORM) {
        __syncthreads();
        if (cg < 8 && t < 32)
            atomicAdd(&nbuf[b * 256 + cg * 32 + t], snorm[t]);
    }
}

// ---------------------------------------------------------------------------
// raw scores S[bh][i][j] += sum_{n chunk} q[n][i]*k[n][j]   (S pre-zeroed)
// ---------------------------------------------------------------------------
__global__ __launch_bounds__(256) void scores(const bf16* __restrict__ qkv,
                                              float* __restrict__ S)
{
    __shared__ short qs[256 * 40];
    __shared__ short ks2[256 * 40];
    const int t = threadIdx.x;
    const int bh = blockIdx.x, b = bh >> 2, h = bh & 3;
    const int n0 = blockIdx.y * 256;
    {
        const short* src = (const short*)qkv + ((size_t)(b * 16384 + n0 + t)) * 384 + h * 32;
#pragma unroll
        for (int i = 0; i < 4; i++) {
            *(s16x8*)&qs[t * 40 + i * 8]  = *(const s16x8*)(src + i * 8);
            *(s16x8*)&ks2[t * 40 + i * 8] = *(const s16x8*)(src + 128 + i * 8);
        }
    }
    __syncthreads();
    const int i2 = t >> 4, j16 = t & 15;
    float a00 = 0.f, a01 = 0.f, a10 = 0.f, a11 = 0.f;
    for (int n = 0; n < 256; n++) {
        unsigned qq = *(const unsigned*)&qs[n * 40 + i2 * 2];
        unsigned kk = *(const unsigned*)&ks2[n * 40 + j16 * 2];
        float q0 = uu2f((unsigned short)(qq & 0xffff)), q1 = uu2f((unsigned short)(qq >> 16));
        float k0 = uu2f((unsigned short)(kk & 0xffff)), k1 = uu2f((unsigned short)(kk >> 16));
        a00 = fmaf(q0, k0, a00); a01 = fmaf(q0, k1, a01);
        a10 = fmaf(q1, k0, a10); a11 = fmaf(q1, k1, a11);
    }
    float* base = S + (size_t)bh * 1024;
    atomicAdd(&base[(i2 * 2 + 0) * 32 + j16 * 2 + 0], a00);
    atomicAdd(&base[(i2 * 2 + 0) * 32 + j16 * 2 + 1], a01);
    atomicAdd(&base[(i2 * 2 + 1) * 32 + j16 * 2 + 0], a10);
    atomicAdd(&base[(i2 * 2 + 1) * 32 + j16 * 2 + 1], a11);
}

// ---------------------------------------------------------------------------
// fused: softmax (temp + q/k norms) on S, then fold proj through attention:
// W2[b][co][h*32+d] = sum_c P[co][h*32+c]*softmax(S)[b,h][c][d].  8 blocks.
// ---------------------------------------------------------------------------
__global__ __launch_bounds__(256) void softmax_fold(
    const float* __restrict__ S, const float* __restrict__ nbuf,
    const float* __restrict__ temp, const bf16* __restrict__ Wprj,
    bf16* __restrict__ W2)
{
    __shared__ float sS[4096];
    __shared__ float sinv[256];
    const int b = blockIdx.x, t = threadIdx.x;
    sinv[t] = 1.f / fmaxf(sqrtf(nbuf[b * 256 + t]), 1e-12f);
    for (int i = t; i < 4096; i += 256) sS[i] = S[b * 4096 + i];
    __syncthreads();
    if (t < 128) {
        int h = t >> 5, i = t & 31;
        float ti = temp[h] * sinv[h * 32 + i];
        float* row = &sS[h * 1024 + i * 32];
        float vals[32], m = -1e30f;
#pragma unroll
        for (int j = 0; j < 32; j++) {
            float v = row[j] * ti * sinv[128 + h * 32 + j];
            vals[j] = v; m = fmaxf(m, v);
        }
        float s = 0.f;
#pragma unroll
        for (int j = 0; j < 32; j++) { vals[j] = expf(vals[j] - m); s += vals[j]; }
        float r = 1.f / s;
#pragma unroll
        for (int j = 0; j < 32; j++) row[j] = vals[j] * r;
    }
    __syncthreads();
    const int co = t >> 1, jh = t & 1;
    const short* prow = (const short*)Wprj + co * 128 + jh * 64;
    float p[64];
#pragma unroll
    for (int i = 0; i < 8; i++) {
        s16x8 v = *(const s16x8*)(prow + i * 8);
#pragma unroll
        for (int e = 0; e < 8; e++) p[i * 8 + e] = uu2f((unsigned short)v[e]);
    }
    short outv[64];
#pragma unroll
    for (int h2 = 0; h2 < 2; h2++) {
        const int h = jh * 2 + h2;
        const float* Sh = &sS[h * 1024];
#pragma unroll 4
        for (int d = 0; d < 32; d++) {
            float a = 0.f;
#pragma unroll
            for (int c = 0; c < 32; c++) a = fmaf(p[h2 * 32 + c], Sh[c * 32 + d], a);
            outv[h2 * 32 + d] = (short)f2us(a);
        }
    }
    short* dst = (short*)W2 + (size_t)b * 16384 + co * 128 + jh * 64;
#pragma unroll
    for (int i = 0; i < 8; i++) *(s16x8*)(dst + i * 8) = *(s16x8*)&outv[i * 8];
}

// ---------------------------------------------------------------------------
extern "C" void kernel_launch(void* const* d_in, const int* in_sizes, int n_in,
                              void* d_out, int out_size, void* d_ws, size_t ws_size,
                              hipStream_t stream)
{
    const float* x_main      = (const float*)d_in[0];
    const float* x_prev      = (const float*)d_in[1];
    const float* x_next      = (const float*)d_in[2];
    const float* alpha_down  = (const float*)d_in[3];
    const float* alpha_up    = (const float*)d_in[4];
    const float* down_w      = (const float*)d_in[5];
    const float* up_w        = (const float*)d_in[6];
    const float* norm1_w     = (const float*)d_in[7];
    const float* norm1_b     = (const float*)d_in[8];
    const float* temperature = (const float*)d_in[9];
    const float* qkv_w       = (const float*)d_in[10];
    const float* qkv_dw_w    = (const float*)d_in[11];
    const float* proj_w      = (const float*)d_in[12];
    const float* norm2_w     = (const float*)d_in[13];
    const float* norm2_b     = (const float*)d_in[14];
    const float* ffn_in_w    = (const float*)d_in[15];
    const float* ffn_dw_w    = (const float*)d_in[16];
    const float* ffn_out_w   = (const float*)d_in[17];
    float* out = (float*)d_out;
    (void)in_sizes; (void)n_in; (void)out_size; (void)ws_size;

    char* ws = (char*)d_ws;
    bf16* xnext_pm = (bf16*)(ws + OFF_XNEXT);
    bf16* up_pm    = (bf16*)(ws + OFF_UP);
    bf16* xprev_pm = (bf16*)(ws + OFF_XPREV);
    bf16* qkv_a    = (bf16*)(ws + OFF_SL1);
    bf16* h1       = (bf16*)(ws + OFF_SL1);
    bf16* qkv_b    = (bf16*)(ws + OFF_SL2);
    bf16* gbuf     = (bf16*)(ws + OFF_SL2);
    bf16* y1       = (bf16*)(ws + OFF_SL3);
    bf16* x_pm     = (bf16*)(ws + OFF_SL4);
    bf16* y2       = (bf16*)(ws + OFF_SL5);
    bf16* Wup      = (bf16*)(ws + OFF_WUP);
    bf16* Wqkv     = (bf16*)(ws + OFF_WQKV);
    bf16* Wprj     = (bf16*)(ws + OFF_WPRJ);
    bf16* Wfin     = (bf16*)(ws + OFF_WFIN);
    bf16* Wfout    = (bf16*)(ws + OFF_WFOUT);
    bf16* Wtap     = (bf16*)(ws + OFF_WTAP);
    bf16* zpage    = (bf16*)(ws + OFF_ZP);
    float* nbuf    = (float*)(ws + OFF_NBUF);
    float* Sbuf    = (float*)(ws + OFF_S);
    bf16* W2buf    = (bf16*)(ws + OFF_W2);

    // all weight prep + zero fills in one dispatch
    prep_all<<<dim3((PREP_TOT + 255) / 256), 256, 0, stream>>>(
        up_w, qkv_w, proj_w, ffn_in_w, ffn_out_w, down_w,
        Wup, Wqkv, Wprj, Wfin, Wfout, Wtap, nbuf, zpage);

    transpose_c2p<<<dim3(128, 8, BATCH), 256, 0, stream>>>(x_next, xnext_pm, 256, 4096);
    transpose_prev<<<dim3(2048, BATCH), 256, 0, stream>>>(x_prev, xprev_pm);

    // up 1x1 conv (GEMM): up_pm[b][4096][512]
    gemm_mfma<0><<<dim3(32, 4, BATCH), 256, 0, stream>>>(
        xnext_pm, Wup, 256, 4096, 512, 512, 256, 0, 0, up_pm,
        nullptr, nullptr, nullptr, nullptr, nullptr, nullptr);

    // down-conv MFMA + residual + shuffle + LN1 -> y1
    down_mfma_ln<<<dim3(128, BATCH), 256, 0, stream>>>(
        xprev_pm, x_main, up_pm, Wtap, alpha_down, alpha_up, norm1_w, norm1_b,
        zpage, y1);

    // qkv 1x1 (GEMM, m-loop): qkv_a[b][16384][384]
    gemm_mloop<0><<<dim3(128, BATCH), 256, 0, stream>>>(y1, Wqkv, 3, 384, 384, qkv_a);

    // depthwise 3x3 -> qkv_b, fused q/k sumsq -> nbuf (8y tile; cg-inner grid)
    dw_conv<0, 1, 8><<<dim3(12, 64, BATCH), 256, 0, stream>>>(qkv_a, qkv_dw_w, qkv_b, nbuf);

    // scores, then fused softmax + proj-fold -> W2
    scores<<<dim3(32, 64), 256, 0, stream>>>(qkv_b, Sbuf);
    softmax_fold<<<dim3(BATCH), 256, 0, stream>>>(Sbuf, nbuf, temperature, Wprj, W2buf);

    // x = x_main + W2 @ v (per-batch weights) + fused LN2 -> x_pm, y2
    gemm_mfma<1><<<dim3(128, 1, BATCH), 256, 0, stream>>>(
        qkv_b, W2buf, 128, NPIX, 128, 128, 384, 256, 16384, y2,
        x_main, x_pm, norm2_w, norm2_b, nullptr, nullptr);

    // ffn_in GEMM -> h1[b][16384][704] (pad cols zeroed in epilogue)
    gemm_mloop<1><<<dim3(128, BATCH), 256, 0, stream>>>(y2, Wfin, 6, 680, H1S, h1);

    // dw + gelu gate -> g[b][16384][352] (4y tile; cg-inner grid)
    dw_conv<1, 0, 4><<<dim3(11, 128, BATCH), 256, 0, stream>>>(h1, ffn_dw_w, gbuf, nullptr);

    // ffn_out GEMM + residual -> out (NCHW f32)
    gemm_mfma<2><<<dim3(128, 1, BATCH), 256, 0, stream>>>(
        gbuf, Wfout, KFF, NPIX, 128, 128, KFF, 0, 0, nullptr,
        nullptr, nullptr, nullptr, nullptr, x_pm, out);
}

// Round 9
// 675.797 us; speedup vs baseline: 1.0042x; 1.0042x over previous
//
#include <hip/hip_runtime.h>
#include <hip/hip_bf16.h>
#include <math.h>

using bf16 = __hip_bfloat16;
#define DEV static __device__ __forceinline__

typedef float    fx4   __attribute__((ext_vector_type(4)));
typedef float    fx2   __attribute__((ext_vector_type(2)));
typedef short    s16x8 __attribute__((ext_vector_type(8)));
typedef short    s16x4 __attribute__((ext_vector_type(4)));
typedef __bf16   bfx8  __attribute__((ext_vector_type(8)));
typedef unsigned int u32x4 __attribute__((ext_vector_type(4)));

constexpr int BATCH = 8;
constexpr int NPIX  = 16384;      // 128x128
constexpr int KFF   = 352;        // padded K for ffn_out
constexpr int MFI   = 768;        // padded M for ffn_in (true 680)
constexpr int H1S   = 704;        // h1 stride: halves at 0 and 352

DEV float uu2f(unsigned short u) { return __uint_as_float(((unsigned)u) << 16); }
DEV unsigned short f2us(float f) { bf16 h = __float2bfloat16(f); return *(unsigned short*)&h; }
DEV float bl2f(bf16 v) { return __bfloat162float(v); }

// ---------------- workspace layout (bytes) ----------------
constexpr size_t OFF_SL1   = 0;                    // {xnext,up,xprev} -> qkv_a -> h1
constexpr size_t OFF_XNEXT = OFF_SL1;              // 16.78MB
constexpr size_t OFF_UP    = OFF_SL1 + 16777216;   // 33.55MB
constexpr size_t OFF_XPREV = OFF_SL1 + 50331648;   // 67.1MB
constexpr size_t SZ_SL1    = 184549376;            // h1 = 8*16384*704*2
constexpr size_t OFF_SL2   = OFF_SL1 + SZ_SL1;     // qkv_b -> g
constexpr size_t OFF_SL3   = OFF_SL2 + 100663296;  // y1
constexpr size_t OFF_SL4   = OFF_SL3 + 33554432;   // x (bf16 pm)
constexpr size_t OFF_SL5   = OFF_SL4 + 33554432;   // y2
constexpr size_t OFF_W     = OFF_SL5 + 33554432;
constexpr size_t OFF_WUP   = OFF_W;                // 512*256*2
constexpr size_t OFF_WQKV  = OFF_W +  262144;      // 384*128*2
constexpr size_t OFF_WPRJ  = OFF_W +  360448;      // 128*128*2
constexpr size_t OFF_WFIN  = OFF_W +  393216;      // 768*128*2
constexpr size_t OFF_WFOUT = OFF_W +  589824;      // 128*352*2
constexpr size_t OFF_WTAP  = OFF_W +  679936;      // 9*128*64*2
constexpr size_t OFF_ZP    = OFF_W +  827392;      // 256B zero page
constexpr size_t OFF_NBUF  = OFF_W +  974848;      // 8*256*4
constexpr size_t OFF_S     = OFF_W +  983040;      // 32*1024*4 (contiguous after nbuf)
constexpr size_t OFF_W2    = OFF_W + 1114112;      // 8*128*128*2

// ---------------------------------------------------------------------------
// one-shot prep: weight converts/permutes + zero fills
// segments: Wup | Wqkv | Wprj | Wfin | Wfout | Wtap | zero(nbuf+S) | zpage
// ---------------------------------------------------------------------------
__global__ void prep_all(const float* __restrict__ up_w, const float* __restrict__ qkv_w,
                         const float* __restrict__ proj_w, const float* __restrict__ ffn_in_w,
                         const float* __restrict__ ffn_out_w, const float* __restrict__ down_w,
                         bf16* __restrict__ Wup, bf16* __restrict__ Wqkv, bf16* __restrict__ Wprj,
                         bf16* __restrict__ Wfin, bf16* __restrict__ Wfout, bf16* __restrict__ Wtap,
                         float* __restrict__ zf, bf16* __restrict__ zpage)
{
    int i = blockIdx.x * 256 + threadIdx.x;
    if (i < 131072) { Wup[i] = __float2bfloat16(up_w[i]); return; }
    i -= 131072;
    if (i < 49152) { Wqkv[i] = __float2bfloat16(qkv_w[i]); return; }
    i -= 49152;
    if (i < 16384) { Wprj[i] = __float2bfloat16(proj_w[i]); return; }
    i -= 16384;
    if (i < 98304) {              // Wfin 768x128 <- 680x128
        Wfin[i] = (i < 680 * 128) ? __float2bfloat16(ffn_in_w[i]) : bf16(0.f);
        return;
    }
    i -= 98304;
    if (i < 45056) {              // Wfout 128x352 <- 128x340
        int r = i / KFF, c = i % KFF;
        Wfout[i] = (c < 340) ? __float2bfloat16(ffn_out_w[r * 340 + c]) : bf16(0.f);
        return;
    }
    i -= 45056;
    if (i < 73728) {              // Wtap [9][128][64] <- [128][64][9]
        int tap = i >> 13, rm = i & 8191, co = rm >> 6, ci = rm & 63;
        Wtap[i] = __float2bfloat16(down_w[(co * 64 + ci) * 9 + tap]);
        return;
    }
    i -= 73728;
    if (i < 34816) { zf[i] = 0.f; return; }   // nbuf (2048) + S (32768)
    i -= 34816;
    if (i < 128) zpage[i] = bf16(0.f);
}
constexpr int PREP_TOT = 131072 + 49152 + 16384 + 98304 + 45056 + 73728 + 34816 + 128;

// NCHW f32 -> pixel-major bf16 transpose (generic, used for x_next C=256)
__global__ __launch_bounds__(256) void transpose_c2p(
    const float* __restrict__ in, bf16* __restrict__ out, int C, int HW)
{
    __shared__ float ts[32][33];
    int hw0 = blockIdx.x * 32, c0 = blockIdx.y * 32, b = blockIdx.z;
    int rl = threadIdx.x >> 5, cl = threadIdx.x & 31;
#pragma unroll
    for (int i = 0; i < 4; i++)
        ts[rl + i * 8][cl] = in[((size_t)b * C + c0 + rl + i * 8) * HW + hw0 + cl];
    __syncthreads();
#pragma unroll
    for (int i = 0; i < 4; i++)
        out[((size_t)b * HW + hw0 + rl + i * 8) * C + c0 + cl] =
            __float2bfloat16(ts[cl][rl + i * 8]);
}

// x_prev transpose (C=64): full-C output rows -> 128B-line writes
__global__ __launch_bounds__(256) void transpose_prev(
    const float* __restrict__ in, bf16* __restrict__ out)
{
    __shared__ float ts[64][33];
    const int hw0 = blockIdx.x * 32, b = blockIdx.y;
    const int cl = threadIdx.x >> 5, hl = threadIdx.x & 31;
#pragma unroll
    for (int i = 0; i < 8; i++) {
        int c = i * 8 + cl;
        ts[c][hl] = in[((size_t)b * 64 + c) * 65536 + hw0 + hl];
    }
    __syncthreads();
    const int hw = threadIdx.x >> 3, c8 = (threadIdx.x & 7) * 8;
    s16x8 pk;
#pragma unroll
    for (int e = 0; e < 8; e++) pk[e] = (short)f2us(ts[c8 + e][hw]);
    *(s16x8*)((short*)out + ((size_t)b * 65536 + hw0 + hw) * 64 + c8) = pk;
}

// ---------------------------------------------------------------------------
// MFMA GEMM (single m-tile): D[b][n][co] = sum_k Act[b][n][Aoff+k] * Wt[b][co][k]
// EPI 0: store bf16 pm; EPI 1: residual+LN2; EPI 2: residual -> f32 NCHW
// ---------------------------------------------------------------------------
template <int EPI>
__global__ __launch_bounds__(256) void gemm_mfma(
    const bf16* __restrict__ Act, const bf16* __restrict__ Wt,
    int K, int Npb, int Mtrue, int Mstride, int Astride, int Aoff, int WtBS,
    bf16* __restrict__ outB,
    const float* __restrict__ xmain, bf16* __restrict__ x_out,
    const float* __restrict__ nw, const float* __restrict__ nb,
    const bf16* __restrict__ xres, float* __restrict__ outF)
{
    __shared__ short As[128 * 32];
    __shared__ short Bs[128 * 32];
    const int t = threadIdx.x;
    const int w = t >> 6, lane = t & 63;
    const int wr = w >> 1, wc = w & 1;
    const int lr = lane & 15, lg = lane >> 4;
    const int n0 = blockIdx.x * 128;
    const int m0 = blockIdx.y * 128;
    const int b  = blockIdx.z;
    const bf16* Abase = Act + (size_t)b * Npb * Astride + Aoff;
    const bf16* Wtb   = Wt + (size_t)b * WtBS;

    fx4 acc[4][4];
#pragma unroll
    for (int i = 0; i < 4; i++)
#pragma unroll
        for (int j = 0; j < 4; j++) acc[i][j] = fx4{0.f, 0.f, 0.f, 0.f};

    const int f0 = w * 128 + lane, f1 = f0 + 64;
    const int r0 = f0 >> 2, c0 = (f0 & 3) * 8;
    const int r1 = f1 >> 2, c1 = (f1 & 3) * 8;

    for (int ks = 0; ks < K; ks += 32) {
        __builtin_amdgcn_global_load_lds(
            (const __attribute__((address_space(1))) void*)(Abase + (size_t)(n0 + r0) * Astride + ks + c0),
            (__attribute__((address_space(3))) void*)(As + w * 1024), 16, 0, 0);
        __builtin_amdgcn_global_load_lds(
            (const __attribute__((address_space(1))) void*)(Abase + (size_t)(n0 + r1) * Astride + ks + c1),
            (__attribute__((address_space(3))) void*)(As + w * 1024 + 512), 16, 0, 0);
        __builtin_amdgcn_global_load_lds(
            (const __attribute__((address_space(1))) void*)(Wtb + (size_t)(m0 + r0) * K + ks + c0),
            (__attribute__((address_space(3))) void*)(Bs + w * 1024), 16, 0, 0);
        __builtin_amdgcn_global_load_lds(
            (const __attribute__((address_space(1))) void*)(Wtb + (size_t)(m0 + r1) * K + ks + c1),
            (__attribute__((address_space(3))) void*)(Bs + w * 1024 + 512), 16, 0, 0);
        __syncthreads();
        bfx8 af[4], bw[4];
#pragma unroll
        for (int mi = 0; mi < 4; mi++)
            af[mi] = __builtin_bit_cast(bfx8,
                *(const s16x8*)&As[(wr * 64 + mi * 16 + lr) * 32 + lg * 8]);
#pragma unroll
        for (int ni = 0; ni < 4; ni++)
            bw[ni] = __builtin_bit_cast(bfx8,
                *(const s16x8*)&Bs[(wc * 64 + ni * 16 + lr) * 32 + lg * 8]);
#pragma unroll
        for (int mi = 0; mi < 4; mi++)
#pragma unroll
            for (int ni = 0; ni < 4; ni++)
                acc[mi][ni] = __builtin_amdgcn_mfma_f32_16x16x32_bf16(
                    af[mi], bw[ni], acc[mi][ni], 0, 0, 0);
        __syncthreads();
    }

    if (EPI == 0) {
#pragma unroll
        for (int mi = 0; mi < 4; mi++)
#pragma unroll
            for (int ni = 0; ni < 4; ni++) {
                int co = m0 + wc * 64 + ni * 16 + lr;
                if (co < Mtrue) {
#pragma unroll
                    for (int r = 0; r < 4; r++) {
                        int px = n0 + wr * 64 + mi * 16 + lg * 4 + r;
                        outB[((size_t)b * Npb + px) * Mstride + co] =
                            __float2bfloat16(acc[mi][ni][r]);
                    }
                }
            }
    } else if (EPI == 1) {
        float xv[4][4][4];
#pragma unroll
        for (int mi = 0; mi < 4; mi++)
#pragma unroll
            for (int ni = 0; ni < 4; ni++) {
                int co = wc * 64 + ni * 16 + lr;
                fx4 x4 = *(const fx4*)&xmain[((size_t)b * 128 + co) * 16384 +
                                             n0 + wr * 64 + mi * 16 + lg * 4];
#pragma unroll
                for (int r = 0; r < 4; r++) xv[mi][ni][r] = x4[r] + acc[mi][ni][r];
            }
        __shared__ float ps[2][128];
        __shared__ float pss[2][128];
#pragma unroll
        for (int mi = 0; mi < 4; mi++)
#pragma unroll
            for (int r = 0; r < 4; r++) {
                float s = 0.f, s2 = 0.f;
#pragma unroll
                for (int ni = 0; ni < 4; ni++) {
                    float v = xv[mi][ni][r]; s += v; s2 += v * v;
                }
#pragma unroll
                for (int m = 1; m < 16; m <<= 1) {
                    s  += __shfl_xor(s, m);
                    s2 += __shfl_xor(s2, m);
                }
                if (lr == 0) {
                    int row = wr * 64 + mi * 16 + lg * 4 + r;
                    ps[wc][row] = s; pss[wc][row] = s2;
                }
            }
        __syncthreads();
        float nwv[4], nbv[4];
#pragma unroll
        for (int ni = 0; ni < 4; ni++) {
            int co = wc * 64 + ni * 16 + lr;
            nwv[ni] = nw[co]; nbv[ni] = nb[co];
        }
#pragma unroll
        for (int mi = 0; mi < 4; mi++)
#pragma unroll
            for (int r = 0; r < 4; r++) {
                int row = wr * 64 + mi * 16 + lg * 4 + r;
                float s  = ps[0][row] + ps[1][row];
                float s2 = pss[0][row] + pss[1][row];
                float mu = s * (1.f / 128.f);
                float var = s2 * (1.f / 128.f) - mu * mu;
                float rstd = rsqrtf(var + 1e-5f);
                size_t px = (size_t)b * 16384 + n0 + row;
#pragma unroll
                for (int ni = 0; ni < 4; ni++) {
                    int co = wc * 64 + ni * 16 + lr;
                    float v = xv[mi][ni][r];
                    x_out[px * 128 + co] = __float2bfloat16(v);
                    outB[px * 128 + co] = __float2bfloat16((v - mu) * rstd * nwv[ni] + nbv[ni]);
                }
            }
    } else {  // EPI 2
#pragma unroll
        for (int mi = 0; mi < 4; mi++)
#pragma unroll
            for (int ni = 0; ni < 4; ni++) {
                int co = wc * 64 + ni * 16 + lr;
                int pxb = n0 + wr * 64 + mi * 16 + lg * 4;
                fx4 o;
#pragma unroll
                for (int r = 0; r < 4; r++)
                    o[r] = acc[mi][ni][r] +
                           bl2f(xres[((size_t)b * 16384 + pxb + r) * 128 + co]);
                *(fx4*)&outF[((size_t)b * 128 + co) * 16384 + pxb] = o;
            }
    }
}

// ---------------------------------------------------------------------------
// MFMA GEMM with m-tile loop (K=128 fixed): stages full A once, loops B tiles.
// REMAP=1: h1 column remap (co>=340 -> co+12), stride 704, pad cols zeroed.
// ---------------------------------------------------------------------------
template <int REMAP>
__global__ __launch_bounds__(256) void gemm_mloop(
    const bf16* __restrict__ Act, const bf16* __restrict__ Wt,
    int nM, int Mtrue, int Mstride, bf16* __restrict__ outB)
{
    __shared__ short As[16384];   // [4 kb][128 row][32]
    __shared__ short Bs[16384];
    const int t = threadIdx.x;
    const int w = t >> 6, lane = t & 63;
    const int wr = w >> 1, wc = w & 1;
    const int lr = lane & 15, lg = lane >> 4;
    const int n0 = blockIdx.x * 128;
    const int b  = blockIdx.y;
    const short* Abase = (const short*)Act + (size_t)b * NPIX * 128;

#pragma unroll
    for (int i = 0; i < 8; i++) {
        int chunk = i * 256 + w * 64 + lane;
        int kb = chunk >> 9, row = (chunk >> 2) & 127, c8 = chunk & 3;
        __builtin_amdgcn_global_load_lds(
            (const __attribute__((address_space(1))) void*)
                (Abase + (size_t)(n0 + row) * 128 + kb * 32 + c8 * 8),
            (__attribute__((address_space(3))) void*)(As + i * 2048 + w * 512), 16, 0, 0);
    }

    for (int mt = 0; mt < nM; mt++) {
#pragma unroll
        for (int i = 0; i < 8; i++) {
            int chunk = i * 256 + w * 64 + lane;
            int kb = chunk >> 9, row = (chunk >> 2) & 127, c8 = chunk & 3;
            __builtin_amdgcn_global_load_lds(
                (const __attribute__((address_space(1))) void*)
                    ((const short*)Wt + (size_t)(mt * 128 + row) * 128 + kb * 32 + c8 * 8),
                (__attribute__((address_space(3))) void*)(Bs + i * 2048 + w * 512), 16, 0, 0);
        }
        __syncthreads();
        fx4 acc[4][4];
#pragma unroll
        for (int i = 0; i < 4; i++)
#pragma unroll
            for (int j = 0; j < 4; j++) acc[i][j] = fx4{0.f, 0.f, 0.f, 0.f};
#pragma unroll
        for (int ks = 0; ks < 4; ks++) {
            bfx8 af[4], bw[4];
#pragma unroll
            for (int mi = 0; mi < 4; mi++)
                af[mi] = __builtin_bit_cast(bfx8,
                    *(const s16x8*)&As[ks * 4096 + (wr * 64 + mi * 16 + lr) * 32 + lg * 8]);
#pragma unroll
            for (int ni = 0; ni < 4; ni++)
                bw[ni] = __builtin_bit_cast(bfx8,
                    *(const s16x8*)&Bs[ks * 4096 + (wc * 64 + ni * 16 + lr) * 32 + lg * 8]);
#pragma unroll
            for (int mi = 0; mi < 4; mi++)
#pragma unroll
                for (int ni = 0; ni < 4; ni++)
                    acc[mi][ni] = __builtin_amdgcn_mfma_f32_16x16x32_bf16(
                        af[mi], bw[ni], acc[mi][ni], 0, 0, 0);
        }
        __syncthreads();
#pragma unroll
        for (int mi = 0; mi < 4; mi++)
#pragma unroll
            for (int ni = 0; ni < 4; ni++) {
                int co = mt * 128 + wc * 64 + ni * 16 + lr;
                if (co < Mtrue) {
                    int cd = (REMAP && co >= 340) ? co + 12 : co;
#pragma unroll
                    for (int r = 0; r < 4; r++) {
                        int px = n0 + wr * 64 + mi * 16 + lg * 4 + r;
                        outB[((size_t)b * NPIX + px) * Mstride + cd] =
                            __float2bfloat16(acc[mi][ni][r]);
                    }
                    if (REMAP && co >= 340 && co < 352) {
#pragma unroll
                        for (int r = 0; r < 4; r++) {
                            int px = n0 + wr * 64 + mi * 16 + lg * 4 + r;
                            outB[((size_t)b * NPIX + px) * Mstride + co] = bf16(0.f);
                        }
                    }
                } else if (REMAP && co < 692) {    // zero pad cols 692..703
#pragma unroll
                    for (int r = 0; r < 4; r++) {
                        int px = n0 + wr * 64 + mi * 16 + lg * 4 + r;
                        outB[((size_t)b * NPIX + px) * Mstride + co + 12] = bf16(0.f);
                    }
                }
            }
    }
}

// ---------------------------------------------------------------------------
// down-conv(3x3,s2) as 9-tap MFMA GEMM + residual + pixel-shuffle + LN1 -> y1
// ---------------------------------------------------------------------------
__global__ __launch_bounds__(256) void down_mfma_ln(
    const bf16* __restrict__ xprev_pm,   // [b][65536][64]
    const float* __restrict__ xmain,     // NCHW f32
    const bf16* __restrict__ up_pm,      // [b][4096][512]
    const bf16* __restrict__ wtap,       // [9][128co][64ci]
    const float* __restrict__ alpha_d, const float* __restrict__ alpha_u,
    const float* __restrict__ n1w, const float* __restrict__ n1b,
    const bf16* __restrict__ zeropage,
    bf16* __restrict__ y1)               // [b][16384][128]
{
    __shared__ short As[128 * 64];
    __shared__ short Bs[128 * 64];
    __shared__ float ps[2][128];
    __shared__ float pss[2][128];
    const int t = threadIdx.x;
    const int w = t >> 6, lane = t & 63;
    const int wr = w >> 1, wc = w & 1;
    const int lr = lane & 15, lg = lane >> 4;
    const int y = blockIdx.x;
    const int b = blockIdx.y;

    const int srow0 = 32 * w + (lane >> 3);
    const int sci8  = lane & 7;
    const short* wtbase = (const short*)wtap;

    fx4 acc[4][4];
#pragma unroll
    for (int i = 0; i < 4; i++)
#pragma unroll
        for (int j = 0; j < 4; j++) acc[i][j] = fx4{0.f, 0.f, 0.f, 0.f};

#pragma unroll
    for (int tap = 0; tap < 9; tap++) {
        const int dy = tap / 3, dx = tap % 3;
        const int iy = 2 * y - 1 + dy;
        const bool rowok = (iy >= 0) && (iy < 256);
        const short* arow = (const short*)xprev_pm +
                            (((size_t)b * 65536 + (size_t)iy * 256) * 64);
#pragma unroll
        for (int i = 0; i < 4; i++) {
            int row = srow0 + 8 * i;
            int ix = 2 * row - 1 + dx;
            const short* src = (rowok && ix >= 0 && ix < 256)
                                 ? (arow + (size_t)ix * 64 + sci8 * 8)
                                 : (const short*)zeropage;
            __builtin_amdgcn_global_load_lds(
                (const __attribute__((address_space(1))) void*)src,
                (__attribute__((address_space(3))) void*)(As + w * 2048 + i * 512), 16, 0, 0);
            __builtin_amdgcn_global_load_lds(
                (const __attribute__((address_space(1))) void*)
                    (wtbase + tap * 8192 + w * 2048 + i * 512 + lane * 8),
                (__attribute__((address_space(3))) void*)(Bs + w * 2048 + i * 512), 16, 0, 0);
        }
        __syncthreads();
        bfx8 af[4][2], bw[4][2];
#pragma unroll
        for (int mi = 0; mi < 4; mi++)
#pragma unroll
            for (int ks = 0; ks < 2; ks++)
                af[mi][ks] = __builtin_bit_cast(bfx8,
                    *(const s16x8*)&As[(wr * 64 + mi * 16 + lr) * 64 + ks * 32 + lg * 8]);
#pragma unroll
        for (int ni = 0; ni < 4; ni++)
#pragma unroll
            for (int ks = 0; ks < 2; ks++)
                bw[ni][ks] = __builtin_bit_cast(bfx8,
                    *(const s16x8*)&Bs[(wc * 64 + ni * 16 + lr) * 64 + ks * 32 + lg * 8]);
#pragma unroll
        for (int mi = 0; mi < 4; mi++)
#pragma unroll
            for (int ni = 0; ni < 4; ni++)
#pragma unroll
                for (int ks = 0; ks < 2; ks++)
                    acc[mi][ni] = __builtin_amdgcn_mfma_f32_16x16x32_bf16(
                        af[mi][ks], bw[ni][ks], acc[mi][ni], 0, 0, 0);
        __syncthreads();
    }

    const float ad = alpha_d[0], au = alpha_u[0];
    const int n2base = (y >> 1) * 64;
    const int chb2 = (y & 1) * 2;
    float fv[4][4][4];
#pragma unroll
    for (int mi = 0; mi < 4; mi++) {
        const int x0 = wr * 64 + mi * 16 + lg * 4;
#pragma unroll
        for (int ni = 0; ni < 4; ni++) {
            const int co = wc * 64 + ni * 16 + lr;
            fx4 xm = *(const fx4*)&xmain[(((size_t)b * 128 + co) * 128 + y) * 128 + x0];
            const short* uprow = (const short*)up_pm +
                ((size_t)b * 4096 + n2base + (x0 >> 1)) * 512 + co * 4 + chb2;
            unsigned up01 = *(const unsigned*)uprow;
            unsigned up23 = *(const unsigned*)(uprow + 512);
            fv[mi][ni][0] = xm[0] + ad * acc[mi][ni][0] + au * uu2f((unsigned short)(up01 & 0xffff));
            fv[mi][ni][1] = xm[1] + ad * acc[mi][ni][1] + au * uu2f((unsigned short)(up01 >> 16));
            fv[mi][ni][2] = xm[2] + ad * acc[mi][ni][2] + au * uu2f((unsigned short)(up23 & 0xffff));
            fv[mi][ni][3] = xm[3] + ad * acc[mi][ni][3] + au * uu2f((unsigned short)(up23 >> 16));
        }
    }
#pragma unroll
    for (int mi = 0; mi < 4; mi++)
#pragma unroll
        for (int r = 0; r < 4; r++) {
            float s = 0.f, s2 = 0.f;
#pragma unroll
            for (int ni = 0; ni < 4; ni++) {
                float v = fv[mi][ni][r]; s += v; s2 += v * v;
            }
#pragma unroll
            for (int m = 1; m < 16; m <<= 1) {
                s  += __shfl_xor(s, m);
                s2 += __shfl_xor(s2, m);
            }
            if (lr == 0) {
                int row = wr * 64 + mi * 16 + lg * 4 + r;
                ps[wc][row] = s; pss[wc][row] = s2;
            }
        }
    __syncthreads();
    float nwv[4], nbv[4];
#pragma unroll
    for (int ni = 0; ni < 4; ni++) {
        int co = wc * 64 + ni * 16 + lr;
        nwv[ni] = n1w[co]; nbv[ni] = n1b[co];
    }
#pragma unroll
    for (int mi = 0; mi < 4; mi++)
#pragma unroll
        for (int r = 0; r < 4; r++) {
            int row = wr * 64 + mi * 16 + lg * 4 + r;
            float s  = ps[0][row] + ps[1][row];
            float s2 = pss[0][row] + pss[1][row];
            float mu = s * (1.f / 128.f);
            float var = s2 * (1.f / 128.f) - mu * mu;
            float rstd = rsqrtf(var + 1e-5f);
            size_t px = (size_t)b * 16384 + (size_t)y * 128 + row;
#pragma unroll
            for (int ni = 0; ni < 4; ni++) {
                int co = wc * 64 + ni * 16 + lr;
                ((short*)y1)[px * 128 + co] =
                    (short)f2us((fv[mi][ni][r] - mu) * rstd * nwv[ni] + nbv[ni]);
            }
        }
}

// ---------------------------------------------------------------------------
// depthwise 3x3 accumulator, templated on YT2 (output rows per thread).
// L: [NROWS][34 pos][44 ch-shorts] (88B = 22 banks -> 2-way free), swb: [9][32] f32
// ---------------------------------------------------------------------------
template <int YT2>
DEV void dw_accum(const short* __restrict__ L, const float* __restrict__ swb,
                  int x, int yh, int lofs, fx2 acc[YT2][4])
{
    fx2 wreg[9][4];
#pragma unroll
    for (int tap = 0; tap < 9; tap++)
#pragma unroll
        for (int k = 0; k < 4; k++)
            wreg[tap][k] = *(const fx2*)&swb[tap * 32 + lofs + 2 * k];
#pragma unroll
    for (int yy = 0; yy < YT2; yy++)
#pragma unroll
        for (int k = 0; k < 4; k++) acc[yy][k] = fx2{0.f, 0.f};
#pragma unroll
    for (int r = 0; r < YT2 + 2; r++) {
        fx2 rv[3][4];
#pragma unroll
        for (int dxp = 0; dxp < 3; dxp++) {
            s16x8 raw = *(const s16x8*)&L[((yh * YT2 + r) * 34 + x + dxp) * 44 + lofs];
            u32x4 u = __builtin_bit_cast(u32x4, raw);
#pragma unroll
            for (int k = 0; k < 4; k++)
                rv[dxp][k] = fx2{__uint_as_float(u[k] << 16),
                                 __uint_as_float(u[k] & 0xffff0000u)};
        }
#pragma unroll
        for (int yy = 0; yy < YT2; yy++) {
            int dy = r - yy;
            if (dy < 0 || dy > 2) continue;
#pragma unroll
            for (int dx = 0; dx < 3; dx++)
#pragma unroll
                for (int k = 0; k < 4; k++)
                    acc[yy][k] += rv[dx][k] * wreg[dy * 3 + dx][k];
        }
    }
}

// ---------------------------------------------------------------------------
// depthwise 3x3 pad=1, pixel-major. GATE=1: gelu(dw(h1a)) * dw(h1b) (both
// halves staged at once); GATE=0: plain (qkv) + q/k sumsq.
// grid: (spatial, cg, b) -- spatial innermost (proven R7 order).
// ---------------------------------------------------------------------------
template <int GATE, int QKNORM, int YTILE>
__global__ __launch_bounds__(256) void dw_conv(
    const bf16* __restrict__ in, const float* __restrict__ w,
    bf16* __restrict__ out, float* __restrict__ nbuf)
{
    constexpr int CHST  = GATE ? 704 : 384;
    constexpr int CHOST = GATE ? 352 : 384;
    constexpr int NROWS = YTILE + 2;
    constexpr int YT2   = YTILE / 2;
    constexpr int LSZ   = NROWS * 34 * 44;
    __shared__ short L1[LSZ];
    __shared__ short L2[GATE ? LSZ : 8];
    __shared__ float sw1[288];                  // [9][32]
    __shared__ float sw2[GATE ? 288 : 8];
    __shared__ float snorm[QKNORM ? 32 : 8];
    const int t = threadIdx.x;
    const int x = t & 31, chg = (t >> 5) & 3, yh = t >> 7;
    const int cg = blockIdx.y, b = blockIdx.z;
    const int sp = blockIdx.x;
    const int x0 = (sp & 3) * 32, y0 = (sp >> 2) * YTILE;

    if (QKNORM && t < 32) snorm[t] = 0.f;
    if (GATE) {
        for (int i = t; i < 288; i += 256) {
            int c = i & 31, tap = i >> 5;
            int cr = cg * 32 + c;
            sw1[i] = (cr < 340) ? w[cr * 9 + tap] : 0.f;
            sw2[i] = (cr < 340) ? w[(cr + 340) * 9 + tap] : 0.f;
        }
    } else {
        for (int i = t; i < 288; i += 256) {
            int c = i & 31, tap = i >> 5;
            sw1[i] = w[(cg * 32 + c) * 9 + tap];
        }
    }
    const short* bin = (const short*)in + (size_t)b * NPIX * CHST + cg * 32;
    constexpr int NCHK1 = NROWS * 136;
    const int NCHK = GATE ? 2 * NCHK1 : NCHK1;
    for (int id = t; id < NCHK; id += 256) {
        int half = 0, idd = id;
        if (GATE && idd >= NCHK1) { half = 1; idd -= NCHK1; }
        int row = idd / 136, rm = idd % 136, pos = rm >> 2, c8 = rm & 3;
        int gy = y0 - 1 + row, gx = x0 - 1 + pos;
        s16x8 v = s16x8{0, 0, 0, 0, 0, 0, 0, 0};
        if (gy >= 0 && gy < 128 && gx >= 0 && gx < 128)
            v = *(const s16x8*)(bin + ((size_t)(gy << 7) + gx) * CHST + half * 352 + c8 * 8);
        short* dst = (GATE && half) ? L2 : L1;
        *(s16x8*)&dst[(row * 34 + pos) * 44 + c8 * 8] = v;
    }
    __syncthreads();

    const int lofs = chg * 8;
    fx2 a1[YT2][4];
    dw_accum<YT2>(L1, sw1, x, yh, lofs, a1);
    if (GATE) {
#pragma unroll
        for (int yy = 0; yy < YT2; yy++)
#pragma unroll
            for (int k = 0; k < 4; k++) {
                fx2 v = a1[yy][k];
#pragma unroll
                for (int e = 0; e < 2; e++) {
                    float xx = v[e];
                    float x2 = xx * xx;
                    float mzz = xx * fmaf(-0.1029432f, x2, -2.3022082f);
                    float un = exp2f(mzz);
                    v[e] = xx * __builtin_amdgcn_rcpf(1.f + un);
                }
                a1[yy][k] = v;
            }
        fx2 a2[YT2][4];
        dw_accum<YT2>(L2, sw2, x, yh, lofs, a2);
#pragma unroll
        for (int yy = 0; yy < YT2; yy++)
#pragma unroll
            for (int k = 0; k < 4; k++) a1[yy][k] *= a2[yy][k];
    }

    if (QKNORM && cg < 8) {
        fx2 sq[4];
#pragma unroll
        for (int k = 0; k < 4; k++) {
            sq[k] = fx2{0.f, 0.f};
#pragma unroll
            for (int yy = 0; yy < YT2; yy++) sq[k] += a1[yy][k] * a1[yy][k];
        }
#pragma unroll
        for (int m = 1; m < 32; m <<= 1)
#pragma unroll
            for (int k = 0; k < 4; k++) {
                sq[k][0] += __shfl_xor(sq[k][0], m);
                sq[k][1] += __shfl_xor(sq[k][1], m);
            }
        if (x == 0) {
#pragma unroll
            for (int k = 0; k < 4; k++) {
                atomicAdd(&snorm[chg * 8 + 2 * k],     sq[k][0]);
                atomicAdd(&snorm[chg * 8 + 2 * k + 1], sq[k][1]);
            }
        }
    }

#pragma unroll
    for (int yy = 0; yy < YT2; yy++) {
        s16x8 pk;
#pragma unroll
        for (int k = 0; k < 4; k++) {
            pk[2 * k]     = (short)f2us(a1[yy][k][0]);
            pk[2 * k + 1] = (short)f2us(a1[yy][k][1]);
        }
        *(s16x8*)((short*)out + (((size_t)b * NPIX) + ((y0 + yh * YT2 + yy) << 7) + x0 + x) * CHOST
                  + cg * 32 + chg * 8) = pk;
    }

    if (QKNORM) {
        __syncthreads();
        if (cg < 8 && t < 32)
            atomicAdd(&nbuf[b * 256 + cg * 32 + t], snorm[t]);
    }
}

// ---------------------------------------------------------------------------
// raw scores S[bh][i][j] += sum_{n chunk} q[n][i]*k[n][j]   (S pre-zeroed)
// ---------------------------------------------------------------------------
__global__ __launch_bounds__(256) void scores(const bf16* __restrict__ qkv,
                                              float* __restrict__ S)
{
    __shared__ short qs[256 * 40];
    __shared__ short ks2[256 * 40];
    const int t = threadIdx.x;
    const int bh = blockIdx.x, b = bh >> 2, h = bh & 3;
    const int n0 = blockIdx.y * 256;
    {
        const short* src = (const short*)qkv + ((size_t)(b * 16384 + n0 + t)) * 384 + h * 32;
#pragma unroll
        for (int i = 0; i < 4; i++) {
            *(s16x8*)&qs[t * 40 + i * 8]  = *(const s16x8*)(src + i * 8);
            *(s16x8*)&ks2[t * 40 + i * 8] = *(const s16x8*)(src + 128 + i * 8);
        }
    }
    __syncthreads();
    const int i2 = t >> 4, j16 = t & 15;
    float a00 = 0.f, a01 = 0.f, a10 = 0.f, a11 = 0.f;
    for (int n = 0; n < 256; n++) {
        unsigned qq = *(const unsigned*)&qs[n * 40 + i2 * 2];
        unsigned kk = *(const unsigned*)&ks2[n * 40 + j16 * 2];
        float q0 = uu2f((unsigned short)(qq & 0xffff)), q1 = uu2f((unsigned short)(qq >> 16));
        float k0 = uu2f((unsigned short)(kk & 0xffff)), k1 = uu2f((unsigned short)(kk >> 16));
        a00 = fmaf(q0, k0, a00); a01 = fmaf(q0, k1, a01);
        a10 = fmaf(q1, k0, a10); a11 = fmaf(q1, k1, a11);
    }
    float* base = S + (size_t)bh * 1024;
    atomicAdd(&base[(i2 * 2 + 0) * 32 + j16 * 2 + 0], a00);
    atomicAdd(&base[(i2 * 2 + 0) * 32 + j16 * 2 + 1], a01);
    atomicAdd(&base[(i2 * 2 + 1) * 32 + j16 * 2 + 0], a10);
    atomicAdd(&base[(i2 * 2 + 1) * 32 + j16 * 2 + 1], a11);
}

// ---------------------------------------------------------------------------
// fused: softmax (temp + q/k norms) on S, then fold proj through attention:
// W2[b][co][h*32+d] = sum_c P[co][h*32+c]*softmax(S)[b,h][c][d].  8 blocks.
// ---------------------------------------------------------------------------
__global__ __launch_bounds__(256) void softmax_fold(
    const float* __restrict__ S, const float* __restrict__ nbuf,
    const float* __restrict__ temp, const bf16* __restrict__ Wprj,
    bf16* __restrict__ W2)
{
    __shared__ float sS[4096];
    __shared__ float sinv[256];
    const int b = blockIdx.x, t = threadIdx.x;
    sinv[t] = 1.f / fmaxf(sqrtf(nbuf[b * 256 + t]), 1e-12f);
    for (int i = t; i < 4096; i += 256) sS[i] = S[b * 4096 + i];
    __syncthreads();
    if (t < 128) {
        int h = t >> 5, i = t & 31;
        float ti = temp[h] * sinv[h * 32 + i];
        float* row = &sS[h * 1024 + i * 32];
        float vals[32], m = -1e30f;
#pragma unroll
        for (int j = 0; j < 32; j++) {
            float v = row[j] * ti * sinv[128 + h * 32 + j];
            vals[j] = v; m = fmaxf(m, v);
        }
        float s = 0.f;
#pragma unroll
        for (int j = 0; j < 32; j++) { vals[j] = expf(vals[j] - m); s += vals[j]; }
        float r = 1.f / s;
#pragma unroll
        for (int j = 0; j < 32; j++) row[j] = vals[j] * r;
    }
    __syncthreads();
    const int co = t >> 1, jh = t & 1;
    const short* prow = (const short*)Wprj + co * 128 + jh * 64;
    float p[64];
#pragma unroll
    for (int i = 0; i < 8; i++) {
        s16x8 v = *(const s16x8*)(prow + i * 8);
#pragma unroll
        for (int e = 0; e < 8; e++) p[i * 8 + e] = uu2f((unsigned short)v[e]);
    }
    short outv[64];
#pragma unroll
    for (int h2 = 0; h2 < 2; h2++) {
        const int h = jh * 2 + h2;
        const float* Sh = &sS[h * 1024];
#pragma unroll 4
        for (int d = 0; d < 32; d++) {
            float a = 0.f;
#pragma unroll
            for (int c = 0; c < 32; c++) a = fmaf(p[h2 * 32 + c], Sh[c * 32 + d], a);
            outv[h2 * 32 + d] = (short)f2us(a);
        }
    }
    short* dst = (short*)W2 + (size_t)b * 16384 + co * 128 + jh * 64;
#pragma unroll
    for (int i = 0; i < 8; i++) *(s16x8*)(dst + i * 8) = *(s16x8*)&outv[i * 8];
}

// ---------------------------------------------------------------------------
extern "C" void kernel_launch(void* const* d_in, const int* in_sizes, int n_in,
                              void* d_out, int out_size, void* d_ws, size_t ws_size,
                              hipStream_t stream)
{
    const float* x_main      = (const float*)d_in[0];
    const float* x_prev      = (const float*)d_in[1];
    const float* x_next      = (const float*)d_in[2];
    const float* alpha_down  = (const float*)d_in[3];
    const float* alpha_up    = (const float*)d_in[4];
    const float* down_w      = (const float*)d_in[5];
    const float* up_w        = (const float*)d_in[6];
    const float* norm1_w     = (const float*)d_in[7];
    const float* norm1_b     = (const float*)d_in[8];
    const float* temperature = (const float*)d_in[9];
    const float* qkv_w       = (const float*)d_in[10];
    const float* qkv_dw_w    = (const float*)d_in[11];
    const float* proj_w      = (const float*)d_in[12];
    const float* norm2_w     = (const float*)d_in[13];
    const float* norm2_b     = (const float*)d_in[14];
    const float* ffn_in_w    = (const float*)d_in[15];
    const float* ffn_dw_w    = (const float*)d_in[16];
    const float* ffn_out_w   = (const float*)d_in[17];
    float* out = (float*)d_out;
    (void)in_sizes; (void)n_in; (void)out_size; (void)ws_size;

    char* ws = (char*)d_ws;
    bf16* xnext_pm = (bf16*)(ws + OFF_XNEXT);
    bf16* up_pm    = (bf16*)(ws + OFF_UP);
    bf16* xprev_pm = (bf16*)(ws + OFF_XPREV);
    bf16* qkv_a    = (bf16*)(ws + OFF_SL1);
    bf16* h1       = (bf16*)(ws + OFF_SL1);
    bf16* qkv_b    = (bf16*)(ws + OFF_SL2);
    bf16* gbuf     = (bf16*)(ws + OFF_SL2);
    bf16* y1       = (bf16*)(ws + OFF_SL3);
    bf16* x_pm     = (bf16*)(ws + OFF_SL4);
    bf16* y2       = (bf16*)(ws + OFF_SL5);
    bf16* Wup      = (bf16*)(ws + OFF_WUP);
    bf16* Wqkv     = (bf16*)(ws + OFF_WQKV);
    bf16* Wprj     = (bf16*)(ws + OFF_WPRJ);
    bf16* Wfin     = (bf16*)(ws + OFF_WFIN);
    bf16* Wfout    = (bf16*)(ws + OFF_WFOUT);
    bf16* Wtap     = (bf16*)(ws + OFF_WTAP);
    bf16* zpage    = (bf16*)(ws + OFF_ZP);
    float* nbuf    = (float*)(ws + OFF_NBUF);
    float* Sbuf    = (float*)(ws + OFF_S);
    bf16* W2buf    = (bf16*)(ws + OFF_W2);

    // all weight prep + zero fills in one dispatch
    prep_all<<<dim3((PREP_TOT + 255) / 256), 256, 0, stream>>>(
        up_w, qkv_w, proj_w, ffn_in_w, ffn_out_w, down_w,
        Wup, Wqkv, Wprj, Wfin, Wfout, Wtap, nbuf, zpage);

    transpose_c2p<<<dim3(128, 8, BATCH), 256, 0, stream>>>(x_next, xnext_pm, 256, 4096);
    transpose_prev<<<dim3(2048, BATCH), 256, 0, stream>>>(x_prev, xprev_pm);

    // up 1x1 conv (GEMM): up_pm[b][4096][512]
    gemm_mfma<0><<<dim3(32, 4, BATCH), 256, 0, stream>>>(
        xnext_pm, Wup, 256, 4096, 512, 512, 256, 0, 0, up_pm,
        nullptr, nullptr, nullptr, nullptr, nullptr, nullptr);

    // down-conv MFMA + residual + shuffle + LN1 -> y1
    down_mfma_ln<<<dim3(128, BATCH), 256, 0, stream>>>(
        xprev_pm, x_main, up_pm, Wtap, alpha_down, alpha_up, norm1_w, norm1_b,
        zpage, y1);

    // qkv 1x1 (GEMM, m-loop): qkv_a[b][16384][384]
    gemm_mloop<0><<<dim3(128, BATCH), 256, 0, stream>>>(y1, Wqkv, 3, 384, 384, qkv_a);

    // depthwise 3x3 -> qkv_b, fused q/k sumsq -> nbuf (8y tile; spatial-inner grid)
    dw_conv<0, 1, 8><<<dim3(64, 12, BATCH), 256, 0, stream>>>(qkv_a, qkv_dw_w, qkv_b, nbuf);

    // scores, then fused softmax + proj-fold -> W2
    scores<<<dim3(32, 64), 256, 0, stream>>>(qkv_b, Sbuf);
    softmax_fold<<<dim3(BATCH), 256, 0, stream>>>(Sbuf, nbuf, temperature, Wprj, W2buf);

    // x = x_main + W2 @ v (per-batch weights) + fused LN2 -> x_pm, y2
    gemm_mfma<1><<<dim3(128, 1, BATCH), 256, 0, stream>>>(
        qkv_b, W2buf, 128, NPIX, 128, 128, 384, 256, 16384, y2,
        x_main, x_pm, norm2_w, norm2_b, nullptr, nullptr);

    // ffn_in GEMM -> h1[b][16384][704] (pad cols zeroed in epilogue)
    gemm_mloop<1><<<dim3(128, BATCH), 256, 0, stream>>>(y2, Wfin, 6, 680, H1S, h1);

    // dw + gelu gate -> g[b][16384][352] (4y tile; spatial-inner grid)
    dw_conv<1, 0, 4><<<dim3(128, 11, BATCH), 256, 0, stream>>>(h1, ffn_dw_w, gbuf, nullptr);

    // ffn_out GEMM + residual -> out (NCHW f32)
    gemm_mfma<2><<<dim3(128, 1, BATCH), 256, 0, stream>>>(
        gbuf, Wfout, KFF, NPIX, 128, 128, KFF, 0, 0, nullptr,
        nullptr, nullptr, nullptr, nullptr, x_pm, out);
}

// Round 10
// 578.907 us; speedup vs baseline: 1.1723x; 1.1674x over previous
//
#include <hip/hip_runtime.h>
#include <hip/hip_bf16.h>
#include <math.h>

using bf16 = __hip_bfloat16;
#define DEV static __device__ __forceinline__

typedef float    fx4   __attribute__((ext_vector_type(4)));
typedef float    fx2   __attribute__((ext_vector_type(2)));
typedef short    s16x8 __attribute__((ext_vector_type(8)));
typedef short    s16x4 __attribute__((ext_vector_type(4)));
typedef __bf16   bfx8  __attribute__((ext_vector_type(8)));
typedef unsigned int u32x4 __attribute__((ext_vector_type(4)));

constexpr int BATCH = 8;
constexpr int NPIX  = 16384;      // 128x128
constexpr int KFF   = 352;        // padded K for ffn_out
constexpr int MFI   = 768;        // padded M for ffn_in (true 680)
constexpr int H1S   = 704;        // h1 stride: halves at 0 and 352

DEV float uu2f(unsigned short u) { return __uint_as_float(((unsigned)u) << 16); }
DEV unsigned short f2us(float f) { bf16 h = __float2bfloat16(f); return *(unsigned short*)&h; }
DEV float bl2f(bf16 v) { return __bfloat162float(v); }

// ---------------- workspace layout (bytes) ----------------
constexpr size_t OFF_SL1   = 0;                    // {xnext,up,xprev} -> qkv_a -> h1
constexpr size_t OFF_XNEXT = OFF_SL1;              // 16.78MB
constexpr size_t OFF_UP    = OFF_SL1 + 16777216;   // 33.55MB
constexpr size_t OFF_XPREV = OFF_SL1 + 50331648;   // 67.1MB
constexpr size_t SZ_SL1    = 184549376;            // h1 = 8*16384*704*2
constexpr size_t OFF_SL2   = OFF_SL1 + SZ_SL1;     // qkv_b -> g
constexpr size_t OFF_SL3   = OFF_SL2 + 100663296;  // y1
constexpr size_t OFF_SL4   = OFF_SL3 + 33554432;   // x (bf16 pm)
constexpr size_t OFF_SL5   = OFF_SL4 + 33554432;   // y2
constexpr size_t OFF_W     = OFF_SL5 + 33554432;
constexpr size_t OFF_WUP   = OFF_W;                // 512*256*2
constexpr size_t OFF_WQKV  = OFF_W +  262144;      // 384*128*2
constexpr size_t OFF_WPRJ  = OFF_W +  360448;      // 128*128*2
constexpr size_t OFF_WFIN  = OFF_W +  393216;      // 768*128*2
constexpr size_t OFF_WFOUT = OFF_W +  589824;      // 128*352*2
constexpr size_t OFF_WTAP  = OFF_W +  679936;      // 9*128*64*2
constexpr size_t OFF_ZP    = OFF_W +  827392;      // 256B zero page
constexpr size_t OFF_NBUF  = OFF_W +  974848;      // 8*256*4
constexpr size_t OFF_S     = OFF_W +  983040;      // 32*1024*4 (contiguous after nbuf)
constexpr size_t OFF_W2    = OFF_W + 1114112;      // 8*128*128*2

// ---------------------------------------------------------------------------
// one-shot prep: weight converts/permutes + zero fills
// ---------------------------------------------------------------------------
__global__ void prep_all(const float* __restrict__ up_w, const float* __restrict__ qkv_w,
                         const float* __restrict__ proj_w, const float* __restrict__ ffn_in_w,
                         const float* __restrict__ ffn_out_w, const float* __restrict__ down_w,
                         bf16* __restrict__ Wup, bf16* __restrict__ Wqkv, bf16* __restrict__ Wprj,
                         bf16* __restrict__ Wfin, bf16* __restrict__ Wfout, bf16* __restrict__ Wtap,
                         float* __restrict__ zf, bf16* __restrict__ zpage)
{
    int i = blockIdx.x * 256 + threadIdx.x;
    if (i < 131072) { Wup[i] = __float2bfloat16(up_w[i]); return; }
    i -= 131072;
    if (i < 49152) { Wqkv[i] = __float2bfloat16(qkv_w[i]); return; }
    i -= 49152;
    if (i < 16384) { Wprj[i] = __float2bfloat16(proj_w[i]); return; }
    i -= 16384;
    if (i < 98304) {              // Wfin 768x128 <- 680x128
        Wfin[i] = (i < 680 * 128) ? __float2bfloat16(ffn_in_w[i]) : bf16(0.f);
        return;
    }
    i -= 98304;
    if (i < 45056) {              // Wfout 128x352 <- 128x340
        int r = i / KFF, c = i % KFF;
        Wfout[i] = (c < 340) ? __float2bfloat16(ffn_out_w[r * 340 + c]) : bf16(0.f);
        return;
    }
    i -= 45056;
    if (i < 73728) {              // Wtap [9][128][64] <- [128][64][9]
        int tap = i >> 13, rm = i & 8191, co = rm >> 6, ci = rm & 63;
        Wtap[i] = __float2bfloat16(down_w[(co * 64 + ci) * 9 + tap]);
        return;
    }
    i -= 73728;
    if (i < 34816) { zf[i] = 0.f; return; }   // nbuf (2048) + S (32768)
    i -= 34816;
    if (i < 128) zpage[i] = bf16(0.f);
}
constexpr int PREP_TOT = 131072 + 49152 + 16384 + 98304 + 45056 + 73728 + 34816 + 128;

// NCHW f32 -> pixel-major bf16 transpose (generic, used for x_next C=256)
__global__ __launch_bounds__(256) void transpose_c2p(
    const float* __restrict__ in, bf16* __restrict__ out, int C, int HW)
{
    __shared__ float ts[32][33];
    int hw0 = blockIdx.x * 32, c0 = blockIdx.y * 32, b = blockIdx.z;
    int rl = threadIdx.x >> 5, cl = threadIdx.x & 31;
#pragma unroll
    for (int i = 0; i < 4; i++)
        ts[rl + i * 8][cl] = in[((size_t)b * C + c0 + rl + i * 8) * HW + hw0 + cl];
    __syncthreads();
#pragma unroll
    for (int i = 0; i < 4; i++)
        out[((size_t)b * HW + hw0 + rl + i * 8) * C + c0 + cl] =
            __float2bfloat16(ts[cl][rl + i * 8]);
}

// x_prev transpose (C=64): full-C output rows -> 128B-line writes
__global__ __launch_bounds__(256) void transpose_prev(
    const float* __restrict__ in, bf16* __restrict__ out)
{
    __shared__ float ts[64][33];
    const int hw0 = blockIdx.x * 32, b = blockIdx.y;
    const int cl = threadIdx.x >> 5, hl = threadIdx.x & 31;
#pragma unroll
    for (int i = 0; i < 8; i++) {
        int c = i * 8 + cl;
        ts[c][hl] = in[((size_t)b * 64 + c) * 65536 + hw0 + hl];
    }
    __syncthreads();
    const int hw = threadIdx.x >> 3, c8 = (threadIdx.x & 7) * 8;
    s16x8 pk;
#pragma unroll
    for (int e = 0; e < 8; e++) pk[e] = (short)f2us(ts[c8 + e][hw]);
    *(s16x8*)((short*)out + ((size_t)b * 65536 + hw0 + hw) * 64 + c8) = pk;
}

// ---------------------------------------------------------------------------
// MFMA GEMM (single m-tile): D[b][n][co] = sum_k Act[b][n][Aoff+k] * Wt[b][co][k]
// EPI 0: store bf16 pm; EPI 1: residual+LN2; EPI 2: residual -> f32 NCHW
// ---------------------------------------------------------------------------
template <int EPI>
__global__ __launch_bounds__(256) void gemm_mfma(
    const bf16* __restrict__ Act, const bf16* __restrict__ Wt,
    int K, int Npb, int Mtrue, int Mstride, int Astride, int Aoff, int WtBS,
    bf16* __restrict__ outB,
    const float* __restrict__ xmain, bf16* __restrict__ x_out,
    const float* __restrict__ nw, const float* __restrict__ nb,
    const bf16* __restrict__ xres, float* __restrict__ outF)
{
    __shared__ short As[128 * 32];
    __shared__ short Bs[128 * 32];
    const int t = threadIdx.x;
    const int w = t >> 6, lane = t & 63;
    const int wr = w >> 1, wc = w & 1;
    const int lr = lane & 15, lg = lane >> 4;
    const int n0 = blockIdx.x * 128;
    const int m0 = blockIdx.y * 128;
    const int b  = blockIdx.z;
    const bf16* Abase = Act + (size_t)b * Npb * Astride + Aoff;
    const bf16* Wtb   = Wt + (size_t)b * WtBS;

    fx4 acc[4][4];
#pragma unroll
    for (int i = 0; i < 4; i++)
#pragma unroll
        for (int j = 0; j < 4; j++) acc[i][j] = fx4{0.f, 0.f, 0.f, 0.f};

    const int f0 = w * 128 + lane, f1 = f0 + 64;
    const int r0 = f0 >> 2, c0 = (f0 & 3) * 8;
    const int r1 = f1 >> 2, c1 = (f1 & 3) * 8;

    for (int ks = 0; ks < K; ks += 32) {
        __builtin_amdgcn_global_load_lds(
            (const __attribute__((address_space(1))) void*)(Abase + (size_t)(n0 + r0) * Astride + ks + c0),
            (__attribute__((address_space(3))) void*)(As + w * 1024), 16, 0, 0);
        __builtin_amdgcn_global_load_lds(
            (const __attribute__((address_space(1))) void*)(Abase + (size_t)(n0 + r1) * Astride + ks + c1),
            (__attribute__((address_space(3))) void*)(As + w * 1024 + 512), 16, 0, 0);
        __builtin_amdgcn_global_load_lds(
            (const __attribute__((address_space(1))) void*)(Wtb + (size_t)(m0 + r0) * K + ks + c0),
            (__attribute__((address_space(3))) void*)(Bs + w * 1024), 16, 0, 0);
        __builtin_amdgcn_global_load_lds(
            (const __attribute__((address_space(1))) void*)(Wtb + (size_t)(m0 + r1) * K + ks + c1),
            (__attribute__((address_space(3))) void*)(Bs + w * 1024 + 512), 16, 0, 0);
        __syncthreads();
        bfx8 af[4], bw[4];
#pragma unroll
        for (int mi = 0; mi < 4; mi++)
            af[mi] = __builtin_bit_cast(bfx8,
                *(const s16x8*)&As[(wr * 64 + mi * 16 + lr) * 32 + lg * 8]);
#pragma unroll
        for (int ni = 0; ni < 4; ni++)
            bw[ni] = __builtin_bit_cast(bfx8,
                *(const s16x8*)&Bs[(wc * 64 + ni * 16 + lr) * 32 + lg * 8]);
#pragma unroll
        for (int mi = 0; mi < 4; mi++)
#pragma unroll
            for (int ni = 0; ni < 4; ni++)
                acc[mi][ni] = __builtin_amdgcn_mfma_f32_16x16x32_bf16(
                    af[mi], bw[ni], acc[mi][ni], 0, 0, 0);
        __syncthreads();
    }

    if (EPI == 0) {
#pragma unroll
        for (int mi = 0; mi < 4; mi++)
#pragma unroll
            for (int ni = 0; ni < 4; ni++) {
                int co = m0 + wc * 64 + ni * 16 + lr;
                if (co < Mtrue) {
#pragma unroll
                    for (int r = 0; r < 4; r++) {
                        int px = n0 + wr * 64 + mi * 16 + lg * 4 + r;
                        outB[((size_t)b * Npb + px) * Mstride + co] =
                            __float2bfloat16(acc[mi][ni][r]);
                    }
                }
            }
    } else if (EPI == 1) {
        float xv[4][4][4];
#pragma unroll
        for (int mi = 0; mi < 4; mi++)
#pragma unroll
            for (int ni = 0; ni < 4; ni++) {
                int co = wc * 64 + ni * 16 + lr;
                fx4 x4 = *(const fx4*)&xmain[((size_t)b * 128 + co) * 16384 +
                                             n0 + wr * 64 + mi * 16 + lg * 4];
#pragma unroll
                for (int r = 0; r < 4; r++) xv[mi][ni][r] = x4[r] + acc[mi][ni][r];
            }
        __shared__ float ps[2][128];
        __shared__ float pss[2][128];
#pragma unroll
        for (int mi = 0; mi < 4; mi++)
#pragma unroll
            for (int r = 0; r < 4; r++) {
                float s = 0.f, s2 = 0.f;
#pragma unroll
                for (int ni = 0; ni < 4; ni++) {
                    float v = xv[mi][ni][r]; s += v; s2 += v * v;
                }
#pragma unroll
                for (int m = 1; m < 16; m <<= 1) {
                    s  += __shfl_xor(s, m);
                    s2 += __shfl_xor(s2, m);
                }
                if (lr == 0) {
                    int row = wr * 64 + mi * 16 + lg * 4 + r;
                    ps[wc][row] = s; pss[wc][row] = s2;
                }
            }
        __syncthreads();
        float nwv[4], nbv[4];
#pragma unroll
        for (int ni = 0; ni < 4; ni++) {
            int co = wc * 64 + ni * 16 + lr;
            nwv[ni] = nw[co]; nbv[ni] = nb[co];
        }
#pragma unroll
        for (int mi = 0; mi < 4; mi++)
#pragma unroll
            for (int r = 0; r < 4; r++) {
                int row = wr * 64 + mi * 16 + lg * 4 + r;
                float s  = ps[0][row] + ps[1][row];
                float s2 = pss[0][row] + pss[1][row];
                float mu = s * (1.f / 128.f);
                float var = s2 * (1.f / 128.f) - mu * mu;
                float rstd = rsqrtf(var + 1e-5f);
                size_t px = (size_t)b * 16384 + n0 + row;
#pragma unroll
                for (int ni = 0; ni < 4; ni++) {
                    int co = wc * 64 + ni * 16 + lr;
                    float v = xv[mi][ni][r];
                    x_out[px * 128 + co] = __float2bfloat16(v);
                    outB[px * 128 + co] = __float2bfloat16((v - mu) * rstd * nwv[ni] + nbv[ni]);
                }
            }
    } else {  // EPI 2
#pragma unroll
        for (int mi = 0; mi < 4; mi++)
#pragma unroll
            for (int ni = 0; ni < 4; ni++) {
                int co = wc * 64 + ni * 16 + lr;
                int pxb = n0 + wr * 64 + mi * 16 + lg * 4;
                fx4 o;
#pragma unroll
                for (int r = 0; r < 4; r++)
                    o[r] = acc[mi][ni][r] +
                           bl2f(xres[((size_t)b * 16384 + pxb + r) * 128 + co]);
                *(fx4*)&outF[((size_t)b * 128 + co) * 16384 + pxb] = o;
            }
    }
}

// ---------------------------------------------------------------------------
// MFMA GEMM with m-tile loop (K=128 fixed): stages full A once, loops B tiles.
// REMAP=1: h1 column remap (co>=340 -> co+12), stride 704, pad cols zeroed.
// ---------------------------------------------------------------------------
template <int REMAP>
__global__ __launch_bounds__(256) void gemm_mloop(
    const bf16* __restrict__ Act, const bf16* __restrict__ Wt,
    int nM, int Mtrue, int Mstride, bf16* __restrict__ outB)
{
    __shared__ short As[16384];   // [4 kb][128 row][32]
    __shared__ short Bs[16384];
    const int t = threadIdx.x;
    const int w = t >> 6, lane = t & 63;
    const int wr = w >> 1, wc = w & 1;
    const int lr = lane & 15, lg = lane >> 4;
    const int n0 = blockIdx.x * 128;
    const int b  = blockIdx.y;
    const short* Abase = (const short*)Act + (size_t)b * NPIX * 128;

#pragma unroll
    for (int i = 0; i < 8; i++) {
        int chunk = i * 256 + w * 64 + lane;
        int kb = chunk >> 9, row = (chunk >> 2) & 127, c8 = chunk & 3;
        __builtin_amdgcn_global_load_lds(
            (const __attribute__((address_space(1))) void*)
                (Abase + (size_t)(n0 + row) * 128 + kb * 32 + c8 * 8),
            (__attribute__((address_space(3))) void*)(As + i * 2048 + w * 512), 16, 0, 0);
    }

    for (int mt = 0; mt < nM; mt++) {
#pragma unroll
        for (int i = 0; i < 8; i++) {
            int chunk = i * 256 + w * 64 + lane;
            int kb = chunk >> 9, row = (chunk >> 2) & 127, c8 = chunk & 3;
            __builtin_amdgcn_global_load_lds(
                (const __attribute__((address_space(1))) void*)
                    ((const short*)Wt + (size_t)(mt * 128 + row) * 128 + kb * 32 + c8 * 8),
                (__attribute__((address_space(3))) void*)(Bs + i * 2048 + w * 512), 16, 0, 0);
        }
        __syncthreads();
        fx4 acc[4][4];
#pragma unroll
        for (int i = 0; i < 4; i++)
#pragma unroll
            for (int j = 0; j < 4; j++) acc[i][j] = fx4{0.f, 0.f, 0.f, 0.f};
#pragma unroll
        for (int ks = 0; ks < 4; ks++) {
            bfx8 af[4], bw[4];
#pragma unroll
            for (int mi = 0; mi < 4; mi++)
                af[mi] = __builtin_bit_cast(bfx8,
                    *(const s16x8*)&As[ks * 4096 + (wr * 64 + mi * 16 + lr) * 32 + lg * 8]);
#pragma unroll
            for (int ni = 0; ni < 4; ni++)
                bw[ni] = __builtin_bit_cast(bfx8,
                    *(const s16x8*)&Bs[ks * 4096 + (wc * 64 + ni * 16 + lr) * 32 + lg * 8]);
#pragma unroll
            for (int mi = 0; mi < 4; mi++)
#pragma unroll
                for (int ni = 0; ni < 4; ni++)
                    acc[mi][ni] = __builtin_amdgcn_mfma_f32_16x16x32_bf16(
                        af[mi], bw[ni], acc[mi][ni], 0, 0, 0);
        }
        __syncthreads();
#pragma unroll
        for (int mi = 0; mi < 4; mi++)
#pragma unroll
            for (int ni = 0; ni < 4; ni++) {
                int co = mt * 128 + wc * 64 + ni * 16 + lr;
                if (co < Mtrue) {
                    int cd = (REMAP && co >= 340) ? co + 12 : co;
#pragma unroll
                    for (int r = 0; r < 4; r++) {
                        int px = n0 + wr * 64 + mi * 16 + lg * 4 + r;
                        outB[((size_t)b * NPIX + px) * Mstride + cd] =
                            __float2bfloat16(acc[mi][ni][r]);
                    }
                    if (REMAP && co >= 340 && co < 352) {
#pragma unroll
                        for (int r = 0; r < 4; r++) {
                            int px = n0 + wr * 64 + mi * 16 + lg * 4 + r;
                            outB[((size_t)b * NPIX + px) * Mstride + co] = bf16(0.f);
                        }
                    }
                } else if (REMAP && co < 692) {    // zero pad cols 692..703
#pragma unroll
                    for (int r = 0; r < 4; r++) {
                        int px = n0 + wr * 64 + mi * 16 + lg * 4 + r;
                        outB[((size_t)b * NPIX + px) * Mstride + co + 12] = bf16(0.f);
                    }
                }
            }
    }
}

// ---------------------------------------------------------------------------
// down-conv(3x3,s2) as 9-tap MFMA GEMM + residual + pixel-shuffle + LN1 -> y1
// ---------------------------------------------------------------------------
__global__ __launch_bounds__(256) void down_mfma_ln(
    const bf16* __restrict__ xprev_pm,   // [b][65536][64]
    const float* __restrict__ xmain,     // NCHW f32
    const bf16* __restrict__ up_pm,      // [b][4096][512]
    const bf16* __restrict__ wtap,       // [9][128co][64ci]
    const float* __restrict__ alpha_d, const float* __restrict__ alpha_u,
    const float* __restrict__ n1w, const float* __restrict__ n1b,
    const bf16* __restrict__ zeropage,
    bf16* __restrict__ y1)               // [b][16384][128]
{
    __shared__ short As[128 * 64];
    __shared__ short Bs[128 * 64];
    __shared__ float ps[2][128];
    __shared__ float pss[2][128];
    const int t = threadIdx.x;
    const int w = t >> 6, lane = t & 63;
    const int wr = w >> 1, wc = w & 1;
    const int lr = lane & 15, lg = lane >> 4;
    const int y = blockIdx.x;
    const int b = blockIdx.y;

    const int srow0 = 32 * w + (lane >> 3);
    const int sci8  = lane & 7;
    const short* wtbase = (const short*)wtap;

    fx4 acc[4][4];
#pragma unroll
    for (int i = 0; i < 4; i++)
#pragma unroll
        for (int j = 0; j < 4; j++) acc[i][j] = fx4{0.f, 0.f, 0.f, 0.f};

#pragma unroll
    for (int tap = 0; tap < 9; tap++) {
        const int dy = tap / 3, dx = tap % 3;
        const int iy = 2 * y - 1 + dy;
        const bool rowok = (iy >= 0) && (iy < 256);
        const short* arow = (const short*)xprev_pm +
                            (((size_t)b * 65536 + (size_t)iy * 256) * 64);
#pragma unroll
        for (int i = 0; i < 4; i++) {
            int row = srow0 + 8 * i;
            int ix = 2 * row - 1 + dx;
            const short* src = (rowok && ix >= 0 && ix < 256)
                                 ? (arow + (size_t)ix * 64 + sci8 * 8)
                                 : (const short*)zeropage;
            __builtin_amdgcn_global_load_lds(
                (const __attribute__((address_space(1))) void*)src,
                (__attribute__((address_space(3))) void*)(As + w * 2048 + i * 512), 16, 0, 0);
            __builtin_amdgcn_global_load_lds(
                (const __attribute__((address_space(1))) void*)
                    (wtbase + tap * 8192 + w * 2048 + i * 512 + lane * 8),
                (__attribute__((address_space(3))) void*)(Bs + w * 2048 + i * 512), 16, 0, 0);
        }
        __syncthreads();
        bfx8 af[4][2], bw[4][2];
#pragma unroll
        for (int mi = 0; mi < 4; mi++)
#pragma unroll
            for (int ks = 0; ks < 2; ks++)
                af[mi][ks] = __builtin_bit_cast(bfx8,
                    *(const s16x8*)&As[(wr * 64 + mi * 16 + lr) * 64 + ks * 32 + lg * 8]);
#pragma unroll
        for (int ni = 0; ni < 4; ni++)
#pragma unroll
            for (int ks = 0; ks < 2; ks++)
                bw[ni][ks] = __builtin_bit_cast(bfx8,
                    *(const s16x8*)&Bs[(wc * 64 + ni * 16 + lr) * 64 + ks * 32 + lg * 8]);
#pragma unroll
        for (int mi = 0; mi < 4; mi++)
#pragma unroll
            for (int ni = 0; ni < 4; ni++)
#pragma unroll
                for (int ks = 0; ks < 2; ks++)
                    acc[mi][ni] = __builtin_amdgcn_mfma_f32_16x16x32_bf16(
                        af[mi][ks], bw[ni][ks], acc[mi][ni], 0, 0, 0);
        __syncthreads();
    }

    const float ad = alpha_d[0], au = alpha_u[0];
    const int n2base = (y >> 1) * 64;
    const int chb2 = (y & 1) * 2;
    float fv[4][4][4];
#pragma unroll
    for (int mi = 0; mi < 4; mi++) {
        const int x0 = wr * 64 + mi * 16 + lg * 4;
#pragma unroll
        for (int ni = 0; ni < 4; ni++) {
            const int co = wc * 64 + ni * 16 + lr;
            fx4 xm = *(const fx4*)&xmain[(((size_t)b * 128 + co) * 128 + y) * 128 + x0];
            const short* uprow = (const short*)up_pm +
                ((size_t)b * 4096 + n2base + (x0 >> 1)) * 512 + co * 4 + chb2;
            unsigned up01 = *(const unsigned*)uprow;
            unsigned up23 = *(const unsigned*)(uprow + 512);
            fv[mi][ni][0] = xm[0] + ad * acc[mi][ni][0] + au * uu2f((unsigned short)(up01 & 0xffff));
            fv[mi][ni][1] = xm[1] + ad * acc[mi][ni][1] + au * uu2f((unsigned short)(up01 >> 16));
            fv[mi][ni][2] = xm[2] + ad * acc[mi][ni][2] + au * uu2f((unsigned short)(up23 & 0xffff));
            fv[mi][ni][3] = xm[3] + ad * acc[mi][ni][3] + au * uu2f((unsigned short)(up23 >> 16));
        }
    }
#pragma unroll
    for (int mi = 0; mi < 4; mi++)
#pragma unroll
        for (int r = 0; r < 4; r++) {
            float s = 0.f, s2 = 0.f;
#pragma unroll
            for (int ni = 0; ni < 4; ni++) {
                float v = fv[mi][ni][r]; s += v; s2 += v * v;
            }
#pragma unroll
            for (int m = 1; m < 16; m <<= 1) {
                s  += __shfl_xor(s, m);
                s2 += __shfl_xor(s2, m);
            }
            if (lr == 0) {
                int row = wr * 64 + mi * 16 + lg * 4 + r;
                ps[wc][row] = s; pss[wc][row] = s2;
            }
        }
    __syncthreads();
    float nwv[4], nbv[4];
#pragma unroll
    for (int ni = 0; ni < 4; ni++) {
        int co = wc * 64 + ni * 16 + lr;
        nwv[ni] = n1w[co]; nbv[ni] = n1b[co];
    }
#pragma unroll
    for (int mi = 0; mi < 4; mi++)
#pragma unroll
        for (int r = 0; r < 4; r++) {
            int row = wr * 64 + mi * 16 + lg * 4 + r;
            float s  = ps[0][row] + ps[1][row];
            float s2 = pss[0][row] + pss[1][row];
            float mu = s * (1.f / 128.f);
            float var = s2 * (1.f / 128.f) - mu * mu;
            float rstd = rsqrtf(var + 1e-5f);
            size_t px = (size_t)b * 16384 + (size_t)y * 128 + row;
#pragma unroll
            for (int ni = 0; ni < 4; ni++) {
                int co = wc * 64 + ni * 16 + lr;
                ((short*)y1)[px * 128 + co] =
                    (short)f2us((fv[mi][ni][r] - mu) * rstd * nwv[ni] + nbv[ni]);
            }
        }
}

// ---------------------------------------------------------------------------
// depthwise 3x3 accumulator, templated on YT2 (output rows per thread).
// L: [NROWS][34 pos][40 ch-shorts]. Stride MUST be 40 (80B = 5x16B): keeps
// every s16x8 access 16B-aligned (single ds_read_b128). 44 (88B) breaks
// alignment -> compiler splits to b64 pairs -> 1.7x slower (R8/R9 regression).
// 4-way bank conflict at stride 40 is the cheaper evil.
// ---------------------------------------------------------------------------
template <int YT2>
DEV void dw_accum(const short* __restrict__ L, const float* __restrict__ swb,
                  int x, int yh, int lofs, fx2 acc[YT2][4])
{
    fx2 wreg[9][4];
#pragma unroll
    for (int tap = 0; tap < 9; tap++)
#pragma unroll
        for (int k = 0; k < 4; k++)
            wreg[tap][k] = *(const fx2*)&swb[tap * 32 + lofs + 2 * k];
#pragma unroll
    for (int yy = 0; yy < YT2; yy++)
#pragma unroll
        for (int k = 0; k < 4; k++) acc[yy][k] = fx2{0.f, 0.f};
#pragma unroll
    for (int r = 0; r < YT2 + 2; r++) {
        fx2 rv[3][4];
#pragma unroll
        for (int dxp = 0; dxp < 3; dxp++) {
            s16x8 raw = *(const s16x8*)&L[((yh * YT2 + r) * 34 + x + dxp) * 40 + lofs];
            u32x4 u = __builtin_bit_cast(u32x4, raw);
#pragma unroll
            for (int k = 0; k < 4; k++)
                rv[dxp][k] = fx2{__uint_as_float(u[k] << 16),
                                 __uint_as_float(u[k] & 0xffff0000u)};
        }
#pragma unroll
        for (int yy = 0; yy < YT2; yy++) {
            int dy = r - yy;
            if (dy < 0 || dy > 2) continue;
#pragma unroll
            for (int dx = 0; dx < 3; dx++)
#pragma unroll
                for (int k = 0; k < 4; k++)
                    acc[yy][k] += rv[dx][k] * wreg[dy * 3 + dx][k];
        }
    }
}

// ---------------------------------------------------------------------------
// depthwise 3x3 pad=1, pixel-major. GATE=1: gelu(dw(h1a)) * dw(h1b) (both
// halves staged at once); GATE=0: plain (qkv) + q/k sumsq.
// grid: (spatial, cg, b) -- spatial innermost (proven R7 order).
// ---------------------------------------------------------------------------
template <int GATE, int QKNORM, int YTILE>
__global__ __launch_bounds__(256) void dw_conv(
    const bf16* __restrict__ in, const float* __restrict__ w,
    bf16* __restrict__ out, float* __restrict__ nbuf)
{
    constexpr int CHST  = GATE ? 704 : 384;
    constexpr int CHOST = GATE ? 352 : 384;
    constexpr int NROWS = YTILE + 2;
    constexpr int YT2   = YTILE / 2;
    constexpr int LSZ   = NROWS * 34 * 40;
    __shared__ short L1[LSZ];
    __shared__ short L2[GATE ? LSZ : 8];
    __shared__ float sw1[288];                  // [9][32]
    __shared__ float sw2[GATE ? 288 : 8];
    __shared__ float snorm[QKNORM ? 32 : 8];
    const int t = threadIdx.x;
    const int x = t & 31, chg = (t >> 5) & 3, yh = t >> 7;
    const int cg = blockIdx.y, b = blockIdx.z;
    const int sp = blockIdx.x;
    const int x0 = (sp & 3) * 32, y0 = (sp >> 2) * YTILE;

    if (QKNORM && t < 32) snorm[t] = 0.f;
    if (GATE) {
        for (int i = t; i < 288; i += 256) {
            int c = i & 31, tap = i >> 5;
            int cr = cg * 32 + c;
            sw1[i] = (cr < 340) ? w[cr * 9 + tap] : 0.f;
            sw2[i] = (cr < 340) ? w[(cr + 340) * 9 + tap] : 0.f;
        }
    } else {
        for (int i = t; i < 288; i += 256) {
            int c = i & 31, tap = i >> 5;
            sw1[i] = w[(cg * 32 + c) * 9 + tap];
        }
    }
    const short* bin = (const short*)in + (size_t)b * NPIX * CHST + cg * 32;
    constexpr int NCHK1 = NROWS * 136;
    const int NCHK = GATE ? 2 * NCHK1 : NCHK1;
    for (int id = t; id < NCHK; id += 256) {
        int half = 0, idd = id;
        if (GATE && idd >= NCHK1) { half = 1; idd -= NCHK1; }
        int row = idd / 136, rm = idd % 136, pos = rm >> 2, c8 = rm & 3;
        int gy = y0 - 1 + row, gx = x0 - 1 + pos;
        s16x8 v = s16x8{0, 0, 0, 0, 0, 0, 0, 0};
        if (gy >= 0 && gy < 128 && gx >= 0 && gx < 128)
            v = *(const s16x8*)(bin + ((size_t)(gy << 7) + gx) * CHST + half * 352 + c8 * 8);
        short* dst = (GATE && half) ? L2 : L1;
        *(s16x8*)&dst[(row * 34 + pos) * 40 + c8 * 8] = v;
    }
    __syncthreads();

    const int lofs = chg * 8;
    fx2 a1[YT2][4];
    dw_accum<YT2>(L1, sw1, x, yh, lofs, a1);
    if (GATE) {
#pragma unroll
        for (int yy = 0; yy < YT2; yy++)
#pragma unroll
            for (int k = 0; k < 4; k++) {
                fx2 v = a1[yy][k];
#pragma unroll
                for (int e = 0; e < 2; e++) {
                    float xx = v[e];
                    float x2 = xx * xx;
                    float mzz = xx * fmaf(-0.1029432f, x2, -2.3022082f);
                    float un = exp2f(mzz);
                    v[e] = xx * __builtin_amdgcn_rcpf(1.f + un);
                }
                a1[yy][k] = v;
            }
        fx2 a2[YT2][4];
        dw_accum<YT2>(L2, sw2, x, yh, lofs, a2);
#pragma unroll
        for (int yy = 0; yy < YT2; yy++)
#pragma unroll
            for (int k = 0; k < 4; k++) a1[yy][k] *= a2[yy][k];
    }

    if (QKNORM && cg < 8) {
        fx2 sq[4];
#pragma unroll
        for (int k = 0; k < 4; k++) {
            sq[k] = fx2{0.f, 0.f};
#pragma unroll
            for (int yy = 0; yy < YT2; yy++) sq[k] += a1[yy][k] * a1[yy][k];
        }
#pragma unroll
        for (int m = 1; m < 32; m <<= 1)
#pragma unroll
            for (int k = 0; k < 4; k++) {
                sq[k][0] += __shfl_xor(sq[k][0], m);
                sq[k][1] += __shfl_xor(sq[k][1], m);
            }
        if (x == 0) {
#pragma unroll
            for (int k = 0; k < 4; k++) {
                atomicAdd(&snorm[chg * 8 + 2 * k],     sq[k][0]);
                atomicAdd(&snorm[chg * 8 + 2 * k + 1], sq[k][1]);
            }
        }
    }

#pragma unroll
    for (int yy = 0; yy < YT2; yy++) {
        s16x8 pk;
#pragma unroll
        for (int k = 0; k < 4; k++) {
            pk[2 * k]     = (short)f2us(a1[yy][k][0]);
            pk[2 * k + 1] = (short)f2us(a1[yy][k][1]);
        }
        *(s16x8*)((short*)out + (((size_t)b * NPIX) + ((y0 + yh * YT2 + yy) << 7) + x0 + x) * CHOST
                  + cg * 32 + chg * 8) = pk;
    }

    if (QKNORM) {
        __syncthreads();
        if (cg < 8 && t < 32)
            atomicAdd(&nbuf[b * 256 + cg * 32 + t], snorm[t]);
    }
}

// ---------------------------------------------------------------------------
// raw scores S[bh][i][j] += sum_{n chunk} q[n][i]*k[n][j]   (S pre-zeroed)
// ---------------------------------------------------------------------------
__global__ __launch_bounds__(256) void scores(const bf16* __restrict__ qkv,
                                              float* __restrict__ S)
{
    __shared__ short qs[256 * 40];
    __shared__ short ks2[256 * 40];
    const int t = threadIdx.x;
    const int bh = blockIdx.x, b = bh >> 2, h = bh & 3;
    const int n0 = blockIdx.y * 256;
    {
        const short* src = (const short*)qkv + ((size_t)(b * 16384 + n0 + t)) * 384 + h * 32;
#pragma unroll
        for (int i = 0; i < 4; i++) {
            *(s16x8*)&qs[t * 40 + i * 8]  = *(const s16x8*)(src + i * 8);
            *(s16x8*)&ks2[t * 40 + i * 8] = *(const s16x8*)(src + 128 + i * 8);
        }
    }
    __syncthreads();
    const int i2 = t >> 4, j16 = t & 15;
    float a00 = 0.f, a01 = 0.f, a10 = 0.f, a11 = 0.f;
    for (int n = 0; n < 256; n++) {
        unsigned qq = *(const unsigned*)&qs[n * 40 + i2 * 2];
        unsigned kk = *(const unsigned*)&ks2[n * 40 + j16 * 2];
        float q0 = uu2f((unsigned short)(qq & 0xffff)), q1 = uu2f((unsigned short)(qq >> 16));
        float k0 = uu2f((unsigned short)(kk & 0xffff)), k1 = uu2f((unsigned short)(kk >> 16));
        a00 = fmaf(q0, k0, a00); a01 = fmaf(q0, k1, a01);
        a10 = fmaf(q1, k0, a10); a11 = fmaf(q1, k1, a11);
    }
    float* base = S + (size_t)bh * 1024;
    atomicAdd(&base[(i2 * 2 + 0) * 32 + j16 * 2 + 0], a00);
    atomicAdd(&base[(i2 * 2 + 0) * 32 + j16 * 2 + 1], a01);
    atomicAdd(&base[(i2 * 2 + 1) * 32 + j16 * 2 + 0], a10);
    atomicAdd(&base[(i2 * 2 + 1) * 32 + j16 * 2 + 1], a11);
}

// ---------------------------------------------------------------------------
// fused: softmax (temp + q/k norms) on S, then fold proj through attention:
// W2[b][co][h*32+d] = sum_c P[co][h*32+c]*softmax(S)[b,h][c][d].  8 blocks.
// ---------------------------------------------------------------------------
__global__ __launch_bounds__(256) void softmax_fold(
    const float* __restrict__ S, const float* __restrict__ nbuf,
    const float* __restrict__ temp, const bf16* __restrict__ Wprj,
    bf16* __restrict__ W2)
{
    __shared__ float sS[4096];
    __shared__ float sinv[256];
    const int b = blockIdx.x, t = threadIdx.x;
    sinv[t] = 1.f / fmaxf(sqrtf(nbuf[b * 256 + t]), 1e-12f);
    for (int i = t; i < 4096; i += 256) sS[i] = S[b * 4096 + i];
    __syncthreads();
    if (t < 128) {
        int h = t >> 5, i = t & 31;
        float ti = temp[h] * sinv[h * 32 + i];
        float* row = &sS[h * 1024 + i * 32];
        float vals[32], m = -1e30f;
#pragma unroll
        for (int j = 0; j < 32; j++) {
            float v = row[j] * ti * sinv[128 + h * 32 + j];
            vals[j] = v; m = fmaxf(m, v);
        }
        float s = 0.f;
#pragma unroll
        for (int j = 0; j < 32; j++) { vals[j] = expf(vals[j] - m); s += vals[j]; }
        float r = 1.f / s;
#pragma unroll
        for (int j = 0; j < 32; j++) row[j] = vals[j] * r;
    }
    __syncthreads();
    const int co = t >> 1, jh = t & 1;
    const short* prow = (const short*)Wprj + co * 128 + jh * 64;
    float p[64];
#pragma unroll
    for (int i = 0; i < 8; i++) {
        s16x8 v = *(const s16x8*)(prow + i * 8);
#pragma unroll
        for (int e = 0; e < 8; e++) p[i * 8 + e] = uu2f((unsigned short)v[e]);
    }
    short outv[64];
#pragma unroll
    for (int h2 = 0; h2 < 2; h2++) {
        const int h = jh * 2 + h2;
        const float* Sh = &sS[h * 1024];
#pragma unroll 4
        for (int d = 0; d < 32; d++) {
            float a = 0.f;
#pragma unroll
            for (int c = 0; c < 32; c++) a = fmaf(p[h2 * 32 + c], Sh[c * 32 + d], a);
            outv[h2 * 32 + d] = (short)f2us(a);
        }
    }
    short* dst = (short*)W2 + (size_t)b * 16384 + co * 128 + jh * 64;
#pragma unroll
    for (int i = 0; i < 8; i++) *(s16x8*)(dst + i * 8) = *(s16x8*)&outv[i * 8];
}

// ---------------------------------------------------------------------------
extern "C" void kernel_launch(void* const* d_in, const int* in_sizes, int n_in,
                              void* d_out, int out_size, void* d_ws, size_t ws_size,
                              hipStream_t stream)
{
    const float* x_main      = (const float*)d_in[0];
    const float* x_prev      = (const float*)d_in[1];
    const float* x_next      = (const float*)d_in[2];
    const float* alpha_down  = (const float*)d_in[3];
    const float* alpha_up    = (const float*)d_in[4];
    const float* down_w      = (const float*)d_in[5];
    const float* up_w        = (const float*)d_in[6];
    const float* norm1_w     = (const float*)d_in[7];
    const float* norm1_b     = (const float*)d_in[8];
    const float* temperature = (const float*)d_in[9];
    const float* qkv_w       = (const float*)d_in[10];
    const float* qkv_dw_w    = (const float*)d_in[11];
    const float* proj_w      = (const float*)d_in[12];
    const float* norm2_w     = (const float*)d_in[13];
    const float* norm2_b     = (const float*)d_in[14];
    const float* ffn_in_w    = (const float*)d_in[15];
    const float* ffn_dw_w    = (const float*)d_in[16];
    const float* ffn_out_w   = (const float*)d_in[17];
    float* out = (float*)d_out;
    (void)in_sizes; (void)n_in; (void)out_size; (void)ws_size;

    char* ws = (char*)d_ws;
    bf16* xnext_pm = (bf16*)(ws + OFF_XNEXT);
    bf16* up_pm    = (bf16*)(ws + OFF_UP);
    bf16* xprev_pm = (bf16*)(ws + OFF_XPREV);
    bf16* qkv_a    = (bf16*)(ws + OFF_SL1);
    bf16* h1       = (bf16*)(ws + OFF_SL1);
    bf16* qkv_b    = (bf16*)(ws + OFF_SL2);
    bf16* gbuf     = (bf16*)(ws + OFF_SL2);
    bf16* y1       = (bf16*)(ws + OFF_SL3);
    bf16* x_pm     = (bf16*)(ws + OFF_SL4);
    bf16* y2       = (bf16*)(ws + OFF_SL5);
    bf16* Wup      = (bf16*)(ws + OFF_WUP);
    bf16* Wqkv     = (bf16*)(ws + OFF_WQKV);
    bf16* Wprj     = (bf16*)(ws + OFF_WPRJ);
    bf16* Wfin     = (bf16*)(ws + OFF_WFIN);
    bf16* Wfout    = (bf16*)(ws + OFF_WFOUT);
    bf16* Wtap     = (bf16*)(ws + OFF_WTAP);
    bf16* zpage    = (bf16*)(ws + OFF_ZP);
    float* nbuf    = (float*)(ws + OFF_NBUF);
    float* Sbuf    = (float*)(ws + OFF_S);
    bf16* W2buf    = (bf16*)(ws + OFF_W2);

    // all weight prep + zero fills in one dispatch
    prep_all<<<dim3((PREP_TOT + 255) / 256), 256, 0, stream>>>(
        up_w, qkv_w, proj_w, ffn_in_w, ffn_out_w, down_w,
        Wup, Wqkv, Wprj, Wfin, Wfout, Wtap, nbuf, zpage);

    transpose_c2p<<<dim3(128, 8, BATCH), 256, 0, stream>>>(x_next, xnext_pm, 256, 4096);
    transpose_prev<<<dim3(2048, BATCH), 256, 0, stream>>>(x_prev, xprev_pm);

    // up 1x1 conv (GEMM): up_pm[b][4096][512]
    gemm_mfma<0><<<dim3(32, 4, BATCH), 256, 0, stream>>>(
        xnext_pm, Wup, 256, 4096, 512, 512, 256, 0, 0, up_pm,
        nullptr, nullptr, nullptr, nullptr, nullptr, nullptr);

    // down-conv MFMA + residual + shuffle + LN1 -> y1
    down_mfma_ln<<<dim3(128, BATCH), 256, 0, stream>>>(
        xprev_pm, x_main, up_pm, Wtap, alpha_down, alpha_up, norm1_w, norm1_b,
        zpage, y1);

    // qkv 1x1 (GEMM, m-loop): qkv_a[b][16384][384]
    gemm_mloop<0><<<dim3(128, BATCH), 256, 0, stream>>>(y1, Wqkv, 3, 384, 384, qkv_a);

    // depthwise 3x3 -> qkv_b, fused q/k sumsq -> nbuf (8y tile; spatial-inner grid)
    dw_conv<0, 1, 8><<<dim3(64, 12, BATCH), 256, 0, stream>>>(qkv_a, qkv_dw_w, qkv_b, nbuf);

    // scores, then fused softmax + proj-fold -> W2
    scores<<<dim3(32, 64), 256, 0, stream>>>(qkv_b, Sbuf);
    softmax_fold<<<dim3(BATCH), 256, 0, stream>>>(Sbuf, nbuf, temperature, Wprj, W2buf);

    // x = x_main + W2 @ v (per-batch weights) + fused LN2 -> x_pm, y2
    gemm_mfma<1><<<dim3(128, 1, BATCH), 256, 0, stream>>>(
        qkv_b, W2buf, 128, NPIX, 128, 128, 384, 256, 16384, y2,
        x_main, x_pm, norm2_w, norm2_b, nullptr, nullptr);

    // ffn_in GEMM -> h1[b][16384][704] (pad cols zeroed in epilogue)
    gemm_mloop<1><<<dim3(128, BATCH), 256, 0, stream>>>(y2, Wfin, 6, 680, H1S, h1);

    // dw + gelu gate -> g[b][16384][352] (4y tile; spatial-inner grid)
    dw_conv<1, 0, 4><<<dim3(128, 11, BATCH), 256, 0, stream>>>(h1, ffn_dw_w, gbuf, nullptr);

    // ffn_out GEMM + residual -> out (NCHW f32)
    gemm_mfma<2><<<dim3(128, 1, BATCH), 256, 0, stream>>>(
        gbuf, Wfout, KFF, NPIX, 128, 128, KFF, 0, 0, nullptr,
        nullptr, nullptr, nullptr, nullptr, x_pm, out);
}